// Round 1
// baseline (724.397 us; speedup 1.0000x reference)
//
#include <hip/hip_runtime.h>

#define NN 100000
#define NE 1600000
// dims: IN=128, HID=128, LAT=64

// ---------------- CSR build ----------------

__global__ __launch_bounds__(256) void hist_kernel(const int* __restrict__ dst,
                                                   int* __restrict__ counts) {
    int i = blockIdx.x * 256 + threadIdx.x;
    if (i < NE) atomicAdd(&counts[dst[i]], 1);
}

// per-block (1024 elems) sums
__global__ __launch_bounds__(256) void scan_phase1(const int* __restrict__ counts,
                                                   int* __restrict__ blockSums) {
    __shared__ int ws[4];
    int tid = threadIdx.x;
    int lane = tid & 63, wid = tid >> 6;
    int idx = blockIdx.x * 1024 + tid * 4;
    int s = 0;
#pragma unroll
    for (int j = 0; j < 4; j++) if (idx + j < NN) s += counts[idx + j];
    for (int off = 32; off > 0; off >>= 1) s += __shfl_down(s, off, 64);
    if (lane == 0) ws[wid] = s;
    __syncthreads();
    if (tid == 0) blockSums[blockIdx.x] = ws[0] + ws[1] + ws[2] + ws[3];
}

// exclusive scan of block sums (nb ~ 98, serial is fine) + write row_ptr[NN]
__global__ void scan_phase2(const int* __restrict__ blockSums, int* __restrict__ blockOffs,
                            int nb, int* __restrict__ row_ptr) {
    if (threadIdx.x == 0 && blockIdx.x == 0) {
        int acc = 0;
        for (int i = 0; i < nb; i++) { blockOffs[i] = acc; acc += blockSums[i]; }
        row_ptr[NN] = acc;
    }
}

__global__ __launch_bounds__(256) void scan_phase3(const int* __restrict__ counts,
                                                   const int* __restrict__ blockOffs,
                                                   int* __restrict__ row_ptr,
                                                   int* __restrict__ cursor) {
    __shared__ int warpSums[4];
    int tid = threadIdx.x;
    int lane = tid & 63, wid = tid >> 6;
    int idx = blockIdx.x * 1024 + tid * 4;
    int v[4];
#pragma unroll
    for (int j = 0; j < 4; j++) v[j] = (idx + j < NN) ? counts[idx + j] : 0;
    int tsum = v[0] + v[1] + v[2] + v[3];
    int x = tsum;
    for (int off = 1; off < 64; off <<= 1) {
        int y = __shfl_up(x, off, 64);
        if (lane >= off) x += y;
    }
    if (lane == 63) warpSums[wid] = x;
    __syncthreads();
    int wOff = 0;
    for (int w = 0; w < wid; w++) wOff += warpSums[w];
    int g = blockOffs[blockIdx.x] + wOff + x - tsum;  // exclusive prefix for this thread's chunk
#pragma unroll
    for (int j = 0; j < 4; j++) {
        if (idx + j < NN) { row_ptr[idx + j] = g; cursor[idx + j] = g; }
        g += v[j];
    }
}

__global__ __launch_bounds__(256) void scatter_kernel(const int* __restrict__ src,
                                                      const int* __restrict__ dst,
                                                      const float* __restrict__ vals,
                                                      int* __restrict__ cursor,
                                                      int* __restrict__ ssrc,
                                                      float* __restrict__ sval) {
    int i = blockIdx.x * 256 + threadIdx.x;
    if (i < NE) {
        int d = dst[i];
        int p = atomicAdd(&cursor[d], 1);
        ssrc[p] = src[i];
        sval[p] = vals[i];
    }
}

// ---------------- GEMM: C[M,NC] = op(A)[M,128] @ W[128,NC] ----------------
// op(A) = relu(A + bias) when RELU_BIAS. TM=4 rows x TN=16 cols per thread.

template <int NC, bool RELU_BIAS>
__global__ __launch_bounds__(256) void gemm_kernel(const float* __restrict__ A,
                                                   const float* __restrict__ W,
                                                   const float* __restrict__ bias,
                                                   float* __restrict__ C, int M) {
    constexpr int K = 128;
    constexpr int TM = 4, TN = 16;
    constexpr int COLG = NC / TN;       // 8 (NC=128) or 4 (NC=64)
    constexpr int ROWG = 256 / COLG;    // 32 or 64
    constexpr int ROWS = ROWG * TM;     // 128 or 256
    constexpr int G = NC / 4;           // float4 groups per k-row

    __shared__ float Ws[K * NC];
    __shared__ float bs[K];

    int tid = threadIdx.x;
    // Stage W with swizzle: compute reads float4-group L = c4*COLG + tx which must
    // contain c-group cg = tx*4 + c4  =>  L = (cg&3)*COLG + (cg>>2). Bank-conflict-free.
    {
        const float4* Wf4 = (const float4*)W;
        float4* Wsf4 = (float4*)Ws;
        for (int i = tid; i < K * G; i += 256) {
            int k = i / G, cg = i % G;
            int L = (cg & 3) * COLG + (cg >> 2);
            Wsf4[k * G + L] = Wf4[i];
        }
    }
    if (RELU_BIAS) { if (tid < K) bs[tid] = bias[tid]; }
    __syncthreads();

    int tx = tid % COLG, ty = tid / COLG;
    int row0 = blockIdx.x * ROWS + ty * TM;

    float4 acc[TM][4];
#pragma unroll
    for (int r = 0; r < TM; r++)
#pragma unroll
        for (int c = 0; c < 4; c++) acc[r][c] = make_float4(0.f, 0.f, 0.f, 0.f);

    bool rok[TM];
#pragma unroll
    for (int r = 0; r < TM; r++) rok[r] = (row0 + r) < M;

    const float4* Af4 = (const float4*)A;
    const float4* Wsf4 = (const float4*)Ws;

    for (int kk = 0; kk < K; kk += 4) {
        float4 a[TM];
#pragma unroll
        for (int r = 0; r < TM; r++)
            a[r] = rok[r] ? Af4[(size_t)(row0 + r) * (K / 4) + (kk >> 2)]
                          : make_float4(0.f, 0.f, 0.f, 0.f);
#pragma unroll
        for (int j = 0; j < 4; j++) {
            int k = kk + j;
            float av[TM];
#pragma unroll
            for (int r = 0; r < TM; r++) {
                float t = (j == 0) ? a[r].x : (j == 1) ? a[r].y : (j == 2) ? a[r].z : a[r].w;
                if (RELU_BIAS) t = fmaxf(t + bs[k], 0.f);
                av[r] = t;
            }
#pragma unroll
            for (int c4 = 0; c4 < 4; c4++) {
                float4 w = Wsf4[k * G + c4 * COLG + tx];
#pragma unroll
                for (int r = 0; r < TM; r++) {
                    acc[r][c4].x += av[r] * w.x;
                    acc[r][c4].y += av[r] * w.y;
                    acc[r][c4].z += av[r] * w.z;
                    acc[r][c4].w += av[r] * w.w;
                }
            }
        }
    }

    float4* Cf4 = (float4*)C;
#pragma unroll
    for (int r = 0; r < TM; r++) {
        if (!rok[r]) continue;
#pragma unroll
        for (int c4 = 0; c4 < 4; c4++)
            Cf4[(size_t)(row0 + r) * (NC / 4) + tx * 4 + c4] = acc[r][c4];
    }
}

// ---------------- SpMM (gather by dst via CSR) ----------------
// D=128: one wave per node, lane owns 2 dims (float2)

__global__ __launch_bounds__(256) void spmm128_kernel(const int* __restrict__ row_ptr,
                                                      const int* __restrict__ ssrc,
                                                      const float* __restrict__ sval,
                                                      const float* __restrict__ X,
                                                      float* __restrict__ Y) {
    int wid = threadIdx.x >> 6;
    int lane = threadIdx.x & 63;
    int node = blockIdx.x * 4 + wid;
    if (node >= NN) return;
    int e0 = row_ptr[node], e1 = row_ptr[node + 1];
    const float2* X2 = (const float2*)X;
    float2 acc = make_float2(0.f, 0.f);
    for (int e = e0; e < e1; ++e) {
        float v = sval[e];
        int s = ssrc[e];
        float2 xv = X2[(size_t)s * 64 + lane];
        acc.x += v * xv.x;
        acc.y += v * xv.y;
    }
    ((float2*)Y)[(size_t)node * 64 + lane] = acc;
}

// D=64 with output bias: one wave per node, lane owns 1 dim

__global__ __launch_bounds__(256) void spmm64_kernel(const int* __restrict__ row_ptr,
                                                     const int* __restrict__ ssrc,
                                                     const float* __restrict__ sval,
                                                     const float* __restrict__ X,
                                                     const float* __restrict__ b2,
                                                     float* __restrict__ out) {
    int wid = threadIdx.x >> 6;
    int lane = threadIdx.x & 63;
    int node = blockIdx.x * 4 + wid;
    if (node >= NN) return;
    int e0 = row_ptr[node], e1 = row_ptr[node + 1];
    float acc = b2[lane];
    for (int e = e0; e < e1; ++e) {
        acc += sval[e] * X[(size_t)ssrc[e] * 64 + lane];
    }
    out[(size_t)node * 64 + lane] = acc;
}

// ---------------- launch ----------------

extern "C" void kernel_launch(void* const* d_in, const int* in_sizes, int n_in,
                              void* d_out, int out_size, void* d_ws, size_t ws_size,
                              hipStream_t stream) {
    const float* x        = (const float*)d_in[0];
    const int*   edge_src = (const int*)d_in[1];
    const int*   edge_dst = (const int*)d_in[2];
    const float* edge_val = (const float*)d_in[3];
    const float* W1       = (const float*)d_in[4];
    const float* b1       = (const float*)d_in[5];
    const float* W2       = (const float*)d_in[6];
    const float* b2       = (const float*)d_in[7];
    float* out = (float*)d_out;

    char* p = (char*)d_ws;
    auto alloc = [&](size_t bytes) {
        char* q = p;
        p += (bytes + 255) & ~(size_t)255;
        return (void*)q;
    };
    float* t1       = (float*)alloc((size_t)NN * 128 * 4);  // xW1; reused as t2 (hW2)
    float* y1       = (float*)alloc((size_t)NN * 128 * 4);  // spmm(xW1)
    int*   ssrc     = (int*)alloc((size_t)NE * 4);
    float* sval     = (float*)alloc((size_t)NE * 4);
    int*   counts   = (int*)alloc((size_t)NN * 4);
    int*   row_ptr  = (int*)alloc((size_t)(NN + 1) * 4);
    int*   cursor   = (int*)alloc((size_t)NN * 4);
    int*   blockSums = (int*)alloc(512);
    int*   blockOffs = (int*)alloc(512);
    float* t2 = t1;

    const int nb = (NN + 1023) / 1024;  // 98

    hipMemsetAsync(counts, 0, (size_t)NN * 4, stream);
    hist_kernel<<<(NE + 255) / 256, 256, 0, stream>>>(edge_dst, counts);
    scan_phase1<<<nb, 256, 0, stream>>>(counts, blockSums);
    scan_phase2<<<1, 64, 0, stream>>>(blockSums, blockOffs, nb, row_ptr);
    scan_phase3<<<nb, 256, 0, stream>>>(counts, blockOffs, row_ptr, cursor);
    scatter_kernel<<<(NE + 255) / 256, 256, 0, stream>>>(edge_src, edge_dst, edge_val,
                                                         cursor, ssrc, sval);

    // t1 = x @ W1
    gemm_kernel<128, false><<<(NN + 127) / 128, 256, 0, stream>>>(x, W1, nullptr, t1, NN);
    // y1 = spmm(t1)
    spmm128_kernel<<<(NN + 3) / 4, 256, 0, stream>>>(row_ptr, ssrc, sval, t1, y1);
    // t2 = relu(y1 + b1) @ W2
    gemm_kernel<64, true><<<(NN + 255) / 256, 256, 0, stream>>>(y1, W2, b1, t2, NN);
    // out = spmm(t2) + b2
    spmm64_kernel<<<(NN + 3) / 4, 256, 0, stream>>>(row_ptr, ssrc, sval, t2, b2, out);
}

// Round 3
// 529.683 us; speedup vs baseline: 1.3676x; 1.3676x over previous
//
#include <hip/hip_runtime.h>

#define NN 100000
#define NE 1600000
// dims: IN=128, HID=128, LAT=64

// ---------------- helpers ----------------

__device__ __forceinline__ unsigned bf16pack(float a, float b) {
    unsigned ua = __builtin_bit_cast(unsigned, a);
    unsigned ub = __builtin_bit_cast(unsigned, b);
    ua = (ua + 0x7fffu + ((ua >> 16) & 1u)) >> 16;   // RNE
    ub = (ub + 0x7fffu + ((ub >> 16) & 1u)) >> 16;
    return ua | (ub << 16);
}

__device__ __forceinline__ float bf16lo(unsigned u) {
    return __builtin_bit_cast(float, u << 16);
}
__device__ __forceinline__ float bf16hi(unsigned u) {
    return __builtin_bit_cast(float, u & 0xffff0000u);
}

// ---------------- CSR build ----------------

__global__ __launch_bounds__(256) void hist_kernel(const int* __restrict__ dst,
                                                   int* __restrict__ counts) {
    int i = blockIdx.x * 256 + threadIdx.x;
    if (i < NE) atomicAdd(&counts[dst[i]], 1);
}

__global__ __launch_bounds__(256) void scan_phase1(const int* __restrict__ counts,
                                                   int* __restrict__ blockSums) {
    __shared__ int ws[4];
    int tid = threadIdx.x;
    int lane = tid & 63, wid = tid >> 6;
    int idx = blockIdx.x * 1024 + tid * 4;
    int s = 0;
#pragma unroll
    for (int j = 0; j < 4; j++) if (idx + j < NN) s += counts[idx + j];
    for (int off = 32; off > 0; off >>= 1) s += __shfl_down(s, off, 64);
    if (lane == 0) ws[wid] = s;
    __syncthreads();
    if (tid == 0) blockSums[blockIdx.x] = ws[0] + ws[1] + ws[2] + ws[3];
}

__global__ void scan_phase2(const int* __restrict__ blockSums, int* __restrict__ blockOffs,
                            int nb, int* __restrict__ row_ptr) {
    if (threadIdx.x == 0 && blockIdx.x == 0) {
        int acc = 0;
        for (int i = 0; i < nb; i++) { blockOffs[i] = acc; acc += blockSums[i]; }
        row_ptr[NN] = acc;
    }
}

__global__ __launch_bounds__(256) void scan_phase3(const int* __restrict__ counts,
                                                   const int* __restrict__ blockOffs,
                                                   int* __restrict__ row_ptr,
                                                   int* __restrict__ cursor) {
    __shared__ int warpSums[4];
    int tid = threadIdx.x;
    int lane = tid & 63, wid = tid >> 6;
    int idx = blockIdx.x * 1024 + tid * 4;
    int v[4];
#pragma unroll
    for (int j = 0; j < 4; j++) v[j] = (idx + j < NN) ? counts[idx + j] : 0;
    int tsum = v[0] + v[1] + v[2] + v[3];
    int x = tsum;
    for (int off = 1; off < 64; off <<= 1) {
        int y = __shfl_up(x, off, 64);
        if (lane >= off) x += y;
    }
    if (lane == 63) warpSums[wid] = x;
    __syncthreads();
    int wOff = 0;
    for (int w = 0; w < wid; w++) wOff += warpSums[w];
    int g = blockOffs[blockIdx.x] + wOff + x - tsum;
#pragma unroll
    for (int j = 0; j < 4; j++) {
        if (idx + j < NN) { row_ptr[idx + j] = g; cursor[idx + j] = g; }
        g += v[j];
    }
}

__global__ __launch_bounds__(256) void scatter_kernel(const int* __restrict__ src,
                                                      const int* __restrict__ dst,
                                                      const float* __restrict__ vals,
                                                      int* __restrict__ cursor,
                                                      int* __restrict__ ssrc,
                                                      float* __restrict__ sval) {
    int i = blockIdx.x * 256 + threadIdx.x;
    if (i < NE) {
        int d = dst[i];
        int p = atomicAdd(&cursor[d], 1);
        ssrc[p] = src[i];
        sval[p] = vals[i];
    }
}

// ---------------- GEMM: C[M,NC](bf16) = op(A)[M,128](f32) @ W[128,NC](f32) ----------------
// op(A) = relu(A + bias) when RELU_BIAS. TM=4 rows x TN=16 cols per thread.

template <int NC, bool RELU_BIAS>
__global__ __launch_bounds__(256) void gemm_kernel(const float* __restrict__ A,
                                                   const float* __restrict__ W,
                                                   const float* __restrict__ bias,
                                                   unsigned* __restrict__ C,  // bf16x2 packed
                                                   int M) {
    constexpr int K = 128;
    constexpr int TM = 4, TN = 16;
    constexpr int COLG = NC / TN;       // 8 (NC=128) or 4 (NC=64)
    constexpr int ROWG = 256 / COLG;    // 32 or 64
    constexpr int ROWS = ROWG * TM;     // 128 or 256
    constexpr int G = NC / 4;           // float4 groups per k-row

    __shared__ float Ws[K * NC];
    __shared__ float bs[K];

    int tid = threadIdx.x;
    {
        const float4* Wf4 = (const float4*)W;
        float4* Wsf4 = (float4*)Ws;
        for (int i = tid; i < K * G; i += 256) {
            int k = i / G, cg = i % G;
            int L = (cg & 3) * COLG + (cg >> 2);
            Wsf4[k * G + L] = Wf4[i];
        }
    }
    if (RELU_BIAS) { if (tid < K) bs[tid] = bias[tid]; }
    __syncthreads();

    int tx = tid % COLG, ty = tid / COLG;
    int row0 = blockIdx.x * ROWS + ty * TM;

    float4 acc[TM][4];
#pragma unroll
    for (int r = 0; r < TM; r++)
#pragma unroll
        for (int c = 0; c < 4; c++) acc[r][c] = make_float4(0.f, 0.f, 0.f, 0.f);

    bool rok[TM];
#pragma unroll
    for (int r = 0; r < TM; r++) rok[r] = (row0 + r) < M;

    const float4* Af4 = (const float4*)A;
    const float4* Wsf4 = (const float4*)Ws;

    for (int kk = 0; kk < K; kk += 4) {
        float4 a[TM];
#pragma unroll
        for (int r = 0; r < TM; r++)
            a[r] = rok[r] ? Af4[(size_t)(row0 + r) * (K / 4) + (kk >> 2)]
                          : make_float4(0.f, 0.f, 0.f, 0.f);
#pragma unroll
        for (int j = 0; j < 4; j++) {
            int k = kk + j;
            float av[TM];
#pragma unroll
            for (int r = 0; r < TM; r++) {
                float t = (j == 0) ? a[r].x : (j == 1) ? a[r].y : (j == 2) ? a[r].z : a[r].w;
                if (RELU_BIAS) t = fmaxf(t + bs[k], 0.f);
                av[r] = t;
            }
#pragma unroll
            for (int c4 = 0; c4 < 4; c4++) {
                float4 w = Wsf4[k * G + c4 * COLG + tx];
#pragma unroll
                for (int r = 0; r < TM; r++) {
                    acc[r][c4].x += av[r] * w.x;
                    acc[r][c4].y += av[r] * w.y;
                    acc[r][c4].z += av[r] * w.z;
                    acc[r][c4].w += av[r] * w.w;
                }
            }
        }
    }

    // epilogue: pack to bf16 (uint2 = 4 bf16)
    uint2* C2 = (uint2*)C;
#pragma unroll
    for (int r = 0; r < TM; r++) {
        if (!rok[r]) continue;
#pragma unroll
        for (int c4 = 0; c4 < 4; c4++) {
            uint2 pk;
            pk.x = bf16pack(acc[r][c4].x, acc[r][c4].y);
            pk.y = bf16pack(acc[r][c4].z, acc[r][c4].w);
            C2[(size_t)(row0 + r) * (NC / 4) + tx * 4 + c4] = pk;
        }
    }
}

// ---------------- SpMM (gather by dst via CSR), bf16 operand ----------------
// D=128: one wave per node; lane owns dims {2*lane, 2*lane+1} (one bf16x2 uint)

__global__ __launch_bounds__(256) void spmm128_kernel(const int* __restrict__ row_ptr,
                                                      const int* __restrict__ ssrc,
                                                      const float* __restrict__ sval,
                                                      const unsigned* __restrict__ X,  // bf16x2, 64/row
                                                      float* __restrict__ Y) {
    int wid = threadIdx.x >> 6;
    int lane = threadIdx.x & 63;
    int node = blockIdx.x * 4 + wid;
    if (node >= NN) return;
    int e0 = __builtin_amdgcn_readfirstlane(row_ptr[node]);
    int e1 = __builtin_amdgcn_readfirstlane(row_ptr[node + 1]);
    float ax = 0.f, ay = 0.f;
    int e = e0;
    for (; e + 8 <= e1; e += 8) {
        int s[8];
        float v[8];
#pragma unroll
        for (int j = 0; j < 8; j++) { s[j] = ssrc[e + j]; v[j] = sval[e + j]; }
        unsigned u[8];
#pragma unroll
        for (int j = 0; j < 8; j++) u[j] = X[(size_t)s[j] * 64 + lane];
#pragma unroll
        for (int j = 0; j < 8; j++) {
            ax += v[j] * bf16lo(u[j]);
            ay += v[j] * bf16hi(u[j]);
        }
    }
    for (; e < e1; ++e) {
        float v = sval[e];
        unsigned u = X[(size_t)ssrc[e] * 64 + lane];
        ax += v * bf16lo(u);
        ay += v * bf16hi(u);
    }
    ((float2*)Y)[(size_t)node * 64 + lane] = make_float2(ax, ay);
}

// D=64 with output bias: one wave per node, lane owns 1 dim (bf16 ushort)

__global__ __launch_bounds__(256) void spmm64_kernel(const int* __restrict__ row_ptr,
                                                     const int* __restrict__ ssrc,
                                                     const float* __restrict__ sval,
                                                     const unsigned short* __restrict__ X,  // bf16, 64/row
                                                     const float* __restrict__ b2,
                                                     float* __restrict__ out) {
    int wid = threadIdx.x >> 6;
    int lane = threadIdx.x & 63;
    int node = blockIdx.x * 4 + wid;
    if (node >= NN) return;
    int e0 = __builtin_amdgcn_readfirstlane(row_ptr[node]);
    int e1 = __builtin_amdgcn_readfirstlane(row_ptr[node + 1]);
    float acc = b2[lane];
    int e = e0;
    for (; e + 8 <= e1; e += 8) {
        int s[8];
        float v[8];
#pragma unroll
        for (int j = 0; j < 8; j++) { s[j] = ssrc[e + j]; v[j] = sval[e + j]; }
        unsigned short u[8];
#pragma unroll
        for (int j = 0; j < 8; j++) u[j] = X[(size_t)s[j] * 64 + lane];
#pragma unroll
        for (int j = 0; j < 8; j++)
            acc += v[j] * __builtin_bit_cast(float, (unsigned)u[j] << 16);
    }
    for (; e < e1; ++e) {
        acc += sval[e] * __builtin_bit_cast(float, (unsigned)X[(size_t)ssrc[e] * 64 + lane] << 16);
    }
    out[(size_t)node * 64 + lane] = acc;
}

// ---------------- launch ----------------

extern "C" void kernel_launch(void* const* d_in, const int* in_sizes, int n_in,
                              void* d_out, int out_size, void* d_ws, size_t ws_size,
                              hipStream_t stream) {
    const float* x        = (const float*)d_in[0];
    const int*   edge_src = (const int*)d_in[1];
    const int*   edge_dst = (const int*)d_in[2];
    const float* edge_val = (const float*)d_in[3];
    const float* W1       = (const float*)d_in[4];
    const float* b1       = (const float*)d_in[5];
    const float* W2       = (const float*)d_in[6];
    const float* b2       = (const float*)d_in[7];
    float* out = (float*)d_out;

    char* p = (char*)d_ws;
    auto alloc = [&](size_t bytes) {
        char* q = p;
        p += (bytes + 255) & ~(size_t)255;
        return (void*)q;
    };
    unsigned* t1   = (unsigned*)alloc((size_t)NN * 128 * 2);  // xW1 in bf16; reused as t2
    float* y1      = (float*)alloc((size_t)NN * 128 * 4);     // spmm(xW1) fp32
    int*   ssrc    = (int*)alloc((size_t)NE * 4);
    float* sval    = (float*)alloc((size_t)NE * 4);
    int*   counts  = (int*)alloc((size_t)NN * 4);
    int*   row_ptr = (int*)alloc((size_t)(NN + 1) * 4);
    int*   cursor  = (int*)alloc((size_t)NN * 4);
    int*   blockSums = (int*)alloc(512);
    int*   blockOffs = (int*)alloc(512);
    unsigned* t2 = t1;  // t1 dead after spmm128

    const int nb = (NN + 1023) / 1024;  // 98

    (void)hipMemsetAsync(counts, 0, (size_t)NN * 4, stream);
    hist_kernel<<<(NE + 255) / 256, 256, 0, stream>>>(edge_dst, counts);
    scan_phase1<<<nb, 256, 0, stream>>>(counts, blockSums);
    scan_phase2<<<1, 64, 0, stream>>>(blockSums, blockOffs, nb, row_ptr);
    scan_phase3<<<nb, 256, 0, stream>>>(counts, blockOffs, row_ptr, cursor);
    scatter_kernel<<<(NE + 255) / 256, 256, 0, stream>>>(edge_src, edge_dst, edge_val,
                                                         cursor, ssrc, sval);

    // t1 = x @ W1  (bf16 out)
    gemm_kernel<128, false><<<(NN + 127) / 128, 256, 0, stream>>>(x, W1, nullptr, t1, NN);
    // y1 = spmm(t1)
    spmm128_kernel<<<(NN + 3) / 4, 256, 0, stream>>>(row_ptr, ssrc, sval, t1, y1);
    // t2 = relu(y1 + b1) @ W2  (bf16 out)
    gemm_kernel<64, true><<<(NN + 255) / 256, 256, 0, stream>>>(y1, W2, b1, t2, NN);
    // out = spmm(t2) + b2
    spmm64_kernel<<<(NN + 3) / 4, 256, 0, stream>>>(row_ptr, ssrc, sval,
                                                    (const unsigned short*)t2, b2, out);
}

// Round 4
// 422.939 us; speedup vs baseline: 1.7128x; 1.2524x over previous
//
#include <hip/hip_runtime.h>

#define NN 100000
#define NE 1600000
// dims: IN=128, HID=128, LAT=64. NN % 16 == 0.

typedef __attribute__((ext_vector_type(4))) float f32x4;
typedef __attribute__((ext_vector_type(8))) short s16x8;

// ---------------- helpers ----------------

__device__ __forceinline__ unsigned bf16pack(float a, float b) {
    unsigned ua = __builtin_bit_cast(unsigned, a);
    unsigned ub = __builtin_bit_cast(unsigned, b);
    ua = (ua + 0x7fffu + ((ua >> 16) & 1u)) >> 16;   // RNE
    ub = (ub + 0x7fffu + ((ub >> 16) & 1u)) >> 16;
    return ua | (ub << 16);
}
__device__ __forceinline__ unsigned short bf16one(float a) {
    unsigned ua = __builtin_bit_cast(unsigned, a);
    return (unsigned short)((ua + 0x7fffu + ((ua >> 16) & 1u)) >> 16);
}
__device__ __forceinline__ float bf16lo(unsigned u) {
    return __builtin_bit_cast(float, u << 16);
}
__device__ __forceinline__ float bf16hi(unsigned u) {
    return __builtin_bit_cast(float, u & 0xffff0000u);
}

// ---------------- CSR build ----------------

__global__ __launch_bounds__(256) void hist_kernel(const int* __restrict__ dst,
                                                   int* __restrict__ counts) {
    int i = blockIdx.x * 256 + threadIdx.x;
    if (i < NE) atomicAdd(&counts[dst[i]], 1);
}

__global__ __launch_bounds__(256) void scan_phase1(const int* __restrict__ counts,
                                                   int* __restrict__ blockSums) {
    __shared__ int ws[4];
    int tid = threadIdx.x;
    int lane = tid & 63, wid = tid >> 6;
    int idx = blockIdx.x * 1024 + tid * 4;
    int s = 0;
#pragma unroll
    for (int j = 0; j < 4; j++) if (idx + j < NN) s += counts[idx + j];
    for (int off = 32; off > 0; off >>= 1) s += __shfl_down(s, off, 64);
    if (lane == 0) ws[wid] = s;
    __syncthreads();
    if (tid == 0) blockSums[blockIdx.x] = ws[0] + ws[1] + ws[2] + ws[3];
}

// single-wave scan over up to 128 block sums
__global__ void scan_phase2(const int* __restrict__ bs, int* __restrict__ bo,
                            int nb, int* __restrict__ row_ptr) {
    int l = threadIdx.x;  // 64 threads
    int v0 = (l < nb) ? bs[l] : 0;
    int v1 = (l + 64 < nb) ? bs[l + 64] : 0;
    int s0 = v0;
    for (int off = 1; off < 64; off <<= 1) {
        int y = __shfl_up(s0, off, 64);
        if (l >= off) s0 += y;
    }
    int tot0 = __shfl(s0, 63, 64);
    int s1 = v1;
    for (int off = 1; off < 64; off <<= 1) {
        int y = __shfl_up(s1, off, 64);
        if (l >= off) s1 += y;
    }
    if (l < nb) bo[l] = s0 - v0;
    if (l + 64 < nb) bo[l + 64] = tot0 + s1 - v1;
    if (l == 63) row_ptr[NN] = tot0 + s1;
}

__global__ __launch_bounds__(256) void scan_phase3(const int* __restrict__ counts,
                                                   const int* __restrict__ blockOffs,
                                                   int* __restrict__ row_ptr,
                                                   int* __restrict__ cursor) {
    __shared__ int warpSums[4];
    int tid = threadIdx.x;
    int lane = tid & 63, wid = tid >> 6;
    int idx = blockIdx.x * 1024 + tid * 4;
    int v[4];
#pragma unroll
    for (int j = 0; j < 4; j++) v[j] = (idx + j < NN) ? counts[idx + j] : 0;
    int tsum = v[0] + v[1] + v[2] + v[3];
    int x = tsum;
    for (int off = 1; off < 64; off <<= 1) {
        int y = __shfl_up(x, off, 64);
        if (lane >= off) x += y;
    }
    if (lane == 63) warpSums[wid] = x;
    __syncthreads();
    int wOff = 0;
    for (int w = 0; w < wid; w++) wOff += warpSums[w];
    int g = blockOffs[blockIdx.x] + wOff + x - tsum;
#pragma unroll
    for (int j = 0; j < 4; j++) {
        if (idx + j < NN) { row_ptr[idx + j] = g; cursor[idx + j] = g; }
        g += v[j];
    }
}

// packed (src, val) records: one 8B store per edge
__global__ __launch_bounds__(256) void scatter_kernel(const int* __restrict__ src,
                                                      const int* __restrict__ dst,
                                                      const float* __restrict__ vals,
                                                      int* __restrict__ cursor,
                                                      int2* __restrict__ edges) {
    int i = blockIdx.x * 256 + threadIdx.x;
    if (i < NE) {
        int d = dst[i];
        int p = atomicAdd(&cursor[d], 1);
        edges[p] = make_int2(src[i], __builtin_bit_cast(int, vals[i]));
    }
}

// ---------------- W fragment pre-arrangement ----------------
// B-frag layout for mfma_f32_16x16x32_bf16: lane l, elem j holds W[k][n] with
// n = t*16 + (l&15), k = kb*32 + (l>>4)*8 + j.  Stored per-fragment contiguous:
// Wb[((t*4+kb)*64 + l)*8 + j].  W1: t<8, W2: t<4 (K=128 both).

__global__ __launch_bounds__(256) void prep_w_kernel(const float* __restrict__ W1,
                                                     const float* __restrict__ W2,
                                                     unsigned short* __restrict__ W1b,
                                                     unsigned short* __restrict__ W2b) {
    int id = blockIdx.x * 256 + threadIdx.x;  // 0..3071
    if (id < 2048) {
        int f = id >> 6, l = id & 63;
        int t = f >> 2, kb = f & 3;
        int k0 = kb * 32 + (l >> 4) * 8, n = t * 16 + (l & 15);
        unsigned short tmp[8];
#pragma unroll
        for (int j = 0; j < 8; j++) tmp[j] = bf16one(W1[(k0 + j) * 128 + n]);
        *(s16x8*)(W1b + (size_t)id * 8) = *(const s16x8*)tmp;
    } else if (id < 3072) {
        int id2 = id - 2048;
        int f = id2 >> 6, l = id2 & 63;
        int t = f >> 2, kb = f & 3;
        int k0 = kb * 32 + (l >> 4) * 8, n = t * 16 + (l & 15);
        unsigned short tmp[8];
#pragma unroll
        for (int j = 0; j < 8; j++) tmp[j] = bf16one(W2[(k0 + j) * 64 + n]);
        *(s16x8*)(W2b + (size_t)id2 * 8) = *(const s16x8*)tmp;
    }
}

// ---------------- MFMA GEMM: C[M, NT*16](bf16) = op(A)[M,128] @ W ----------------
// A_BF16=false: A fp32, op = identity (GEMM1: x @ W1)
// A_BF16=true:  A bf16, op = relu(A + bias) (GEMM2: relu(y1+b1) @ W2)
// One wave per 16-row m-tile, grid-stride. B frags VGPR-resident.

template <int NT, bool A_BF16>
__global__ __launch_bounds__(256) void gemm_mfma_kernel(const float* __restrict__ Af,
                                                        const unsigned short* __restrict__ Ab,
                                                        const unsigned short* __restrict__ Wb,
                                                        const float* __restrict__ bias,
                                                        unsigned short* __restrict__ C) {
    constexpr int NC = NT * 16;
    int lane = threadIdx.x & 63;
    int wave = (blockIdx.x * 256 + threadIdx.x) >> 6;
    int nwaves = gridDim.x * 4;
    int col = lane & 15;
    int quad = lane >> 4;

    s16x8 bF[NT][4];
#pragma unroll
    for (int t = 0; t < NT; t++)
#pragma unroll
        for (int kb = 0; kb < 4; kb++)
            bF[t][kb] = *(const s16x8*)(Wb + (size_t)((t * 4 + kb) * 64 + lane) * 8);

    const int mtiles = NN / 16;
    for (int mt = wave; mt < mtiles; mt += nwaves) {
        int row = mt * 16 + col;
        s16x8 aF[4];
        if (!A_BF16) {
#pragma unroll
            for (int kb = 0; kb < 4; kb++) {
                const float4* px = (const float4*)(Af + (size_t)row * 128 + kb * 32 + quad * 8);
                float4 f0 = px[0], f1 = px[1];
                unsigned u[4];
                u[0] = bf16pack(f0.x, f0.y);
                u[1] = bf16pack(f0.z, f0.w);
                u[2] = bf16pack(f1.x, f1.y);
                u[3] = bf16pack(f1.z, f1.w);
                aF[kb] = __builtin_bit_cast(s16x8, *(const uint4*)u);
            }
        } else {
#pragma unroll
            for (int kb = 0; kb < 4; kb++) {
                uint4 u = *(const uint4*)(Ab + (size_t)row * 128 + kb * 32 + quad * 8);
                const float4* pb = (const float4*)(bias + kb * 32 + quad * 8);
                float4 b0 = pb[0], b1 = pb[1];
                unsigned r[4];
                r[0] = bf16pack(fmaxf(bf16lo(u.x) + b0.x, 0.f), fmaxf(bf16hi(u.x) + b0.y, 0.f));
                r[1] = bf16pack(fmaxf(bf16lo(u.y) + b0.z, 0.f), fmaxf(bf16hi(u.y) + b0.w, 0.f));
                r[2] = bf16pack(fmaxf(bf16lo(u.z) + b1.x, 0.f), fmaxf(bf16hi(u.z) + b1.y, 0.f));
                r[3] = bf16pack(fmaxf(bf16lo(u.w) + b1.z, 0.f), fmaxf(bf16hi(u.w) + b1.w, 0.f));
                aF[kb] = __builtin_bit_cast(s16x8, *(const uint4*)r);
            }
        }

        f32x4 acc[NT];
#pragma unroll
        for (int t = 0; t < NT; t++) acc[t] = (f32x4){0.f, 0.f, 0.f, 0.f};
#pragma unroll
        for (int kb = 0; kb < 4; kb++)
#pragma unroll
            for (int t = 0; t < NT; t++)
                acc[t] = __builtin_amdgcn_mfma_f32_16x16x32_bf16(aF[kb], bF[t][kb], acc[t], 0, 0, 0);

        int crow = mt * 16 + quad * 4;
#pragma unroll
        for (int t = 0; t < NT; t++)
#pragma unroll
            for (int r = 0; r < 4; r++)
                C[(size_t)(crow + r) * NC + t * 16 + col] = bf16one(acc[t][r]);
    }
}

// ---------------- SpMM (gather by dst via CSR), bf16 operand ----------------
// D=128: one wave per node; lane owns dims {2*lane, 2*lane+1}; bf16 output

__global__ __launch_bounds__(256) void spmm128_kernel(const int* __restrict__ row_ptr,
                                                      const int2* __restrict__ E,
                                                      const unsigned* __restrict__ X,  // bf16x2/row
                                                      unsigned* __restrict__ Yb) {     // bf16x2/row
    int wid = threadIdx.x >> 6;
    int lane = threadIdx.x & 63;
    int node = blockIdx.x * 4 + wid;
    if (node >= NN) return;
    int e0 = __builtin_amdgcn_readfirstlane(row_ptr[node]);
    int e1 = __builtin_amdgcn_readfirstlane(row_ptr[node + 1]);
    float ax = 0.f, ay = 0.f;
    int e = e0;
    for (; e + 8 <= e1; e += 8) {
        int2 ed[8];
#pragma unroll
        for (int j = 0; j < 8; j++) ed[j] = E[e + j];
        unsigned u[8];
#pragma unroll
        for (int j = 0; j < 8; j++) u[j] = X[(size_t)ed[j].x * 64 + lane];
#pragma unroll
        for (int j = 0; j < 8; j++) {
            float v = __builtin_bit_cast(float, ed[j].y);
            ax += v * bf16lo(u[j]);
            ay += v * bf16hi(u[j]);
        }
    }
    for (; e < e1; ++e) {
        int2 ed = E[e];
        float v = __builtin_bit_cast(float, ed.y);
        unsigned u = X[(size_t)ed.x * 64 + lane];
        ax += v * bf16lo(u);
        ay += v * bf16hi(u);
    }
    Yb[(size_t)node * 64 + lane] = bf16pack(ax, ay);
}

// D=64 with output bias: one wave per node, lane owns 1 dim; fp32 output

__global__ __launch_bounds__(256) void spmm64_kernel(const int* __restrict__ row_ptr,
                                                     const int2* __restrict__ E,
                                                     const unsigned short* __restrict__ X,
                                                     const float* __restrict__ b2,
                                                     float* __restrict__ out) {
    int wid = threadIdx.x >> 6;
    int lane = threadIdx.x & 63;
    int node = blockIdx.x * 4 + wid;
    if (node >= NN) return;
    int e0 = __builtin_amdgcn_readfirstlane(row_ptr[node]);
    int e1 = __builtin_amdgcn_readfirstlane(row_ptr[node + 1]);
    float acc = b2[lane];
    int e = e0;
    for (; e + 8 <= e1; e += 8) {
        int2 ed[8];
#pragma unroll
        for (int j = 0; j < 8; j++) ed[j] = E[e + j];
        unsigned short u[8];
#pragma unroll
        for (int j = 0; j < 8; j++) u[j] = X[(size_t)ed[j].x * 64 + lane];
#pragma unroll
        for (int j = 0; j < 8; j++)
            acc += __builtin_bit_cast(float, ed[j].y) *
                   __builtin_bit_cast(float, (unsigned)u[j] << 16);
    }
    for (; e < e1; ++e) {
        int2 ed = E[e];
        acc += __builtin_bit_cast(float, ed.y) *
               __builtin_bit_cast(float, (unsigned)X[(size_t)ed.x * 64 + lane] << 16);
    }
    out[(size_t)node * 64 + lane] = acc;
}

// ---------------- launch ----------------

extern "C" void kernel_launch(void* const* d_in, const int* in_sizes, int n_in,
                              void* d_out, int out_size, void* d_ws, size_t ws_size,
                              hipStream_t stream) {
    const float* x        = (const float*)d_in[0];
    const int*   edge_src = (const int*)d_in[1];
    const int*   edge_dst = (const int*)d_in[2];
    const float* edge_val = (const float*)d_in[3];
    const float* W1       = (const float*)d_in[4];
    const float* b1       = (const float*)d_in[5];
    const float* W2       = (const float*)d_in[6];
    const float* b2       = (const float*)d_in[7];
    float* out = (float*)d_out;

    char* p = (char*)d_ws;
    auto alloc = [&](size_t bytes) {
        char* q = p;
        p += (bytes + 255) & ~(size_t)255;
        return (void*)q;
    };
    unsigned short* t1  = (unsigned short*)alloc((size_t)NN * 128 * 2);  // xW1 bf16; reused as t2
    unsigned short* y1b = (unsigned short*)alloc((size_t)NN * 128 * 2);  // spmm(t1) bf16
    int2* edges         = (int2*)alloc((size_t)NE * 8);
    int*  counts        = (int*)alloc((size_t)NN * 4);
    int*  row_ptr       = (int*)alloc((size_t)(NN + 1) * 4);
    int*  cursor        = (int*)alloc((size_t)NN * 4);
    int*  blockSums     = (int*)alloc(512);
    int*  blockOffs     = (int*)alloc(512);
    unsigned short* W1b = (unsigned short*)alloc(2048 * 8 * 2);  // 32 KB
    unsigned short* W2b = (unsigned short*)alloc(1024 * 8 * 2);  // 16 KB
    unsigned short* t2 = t1;  // t1 dead after spmm128

    const int nb = (NN + 1023) / 1024;  // 98

    (void)hipMemsetAsync(counts, 0, (size_t)NN * 4, stream);
    prep_w_kernel<<<12, 256, 0, stream>>>(W1, W2, W1b, W2b);
    hist_kernel<<<(NE + 255) / 256, 256, 0, stream>>>(edge_dst, counts);
    scan_phase1<<<nb, 256, 0, stream>>>(counts, blockSums);
    scan_phase2<<<1, 64, 0, stream>>>(blockSums, blockOffs, nb, row_ptr);
    scan_phase3<<<nb, 256, 0, stream>>>(counts, blockOffs, row_ptr, cursor);
    scatter_kernel<<<(NE + 255) / 256, 256, 0, stream>>>(edge_src, edge_dst, edge_val,
                                                         cursor, edges);

    // t1 = bf16(x) @ W1
    gemm_mfma_kernel<8, false><<<256, 256, 0, stream>>>(x, nullptr, W1b, nullptr, t1);
    // y1b = spmm(t1)  (bf16 out)
    spmm128_kernel<<<(NN + 3) / 4, 256, 0, stream>>>(row_ptr, edges, (const unsigned*)t1, (unsigned*)y1b);
    // t2 = relu(y1b + b1) @ W2
    gemm_mfma_kernel<4, true><<<256, 256, 0, stream>>>(nullptr, y1b, W2b, b1, t2);
    // out = spmm(t2) + b2
    spmm64_kernel<<<(NN + 3) / 4, 256, 0, stream>>>(row_ptr, edges, t2, b2, out);
}

// Round 5
// 319.463 us; speedup vs baseline: 2.2675x; 1.3239x over previous
//
#include <hip/hip_runtime.h>

#define NN 100000
#define NE 1600000
// dims: IN=128, HID=128, LAT=64. NN % 16 == 0.

#define B_NODES 512      // nodes per coarse bucket (2^9)
#define NB 196           // ceil(NN / B_NODES)
#define CH 8192          // edges per partition block
#define NCHUNK 196       // ceil(NE / CH)

typedef __attribute__((ext_vector_type(4))) float f32x4;
typedef __attribute__((ext_vector_type(8))) short s16x8;

// ---------------- helpers ----------------

__device__ __forceinline__ unsigned bf16pack(float a, float b) {
    unsigned ua = __builtin_bit_cast(unsigned, a);
    unsigned ub = __builtin_bit_cast(unsigned, b);
    ua = (ua + 0x7fffu + ((ua >> 16) & 1u)) >> 16;   // RNE
    ub = (ub + 0x7fffu + ((ub >> 16) & 1u)) >> 16;
    return ua | (ub << 16);
}
__device__ __forceinline__ unsigned short bf16one(float a) {
    unsigned ua = __builtin_bit_cast(unsigned, a);
    return (unsigned short)((ua + 0x7fffu + ((ua >> 16) & 1u)) >> 16);
}
__device__ __forceinline__ float bf16lo(unsigned u) {
    return __builtin_bit_cast(float, u << 16);
}
__device__ __forceinline__ float bf16hi(unsigned u) {
    return __builtin_bit_cast(float, u & 0xffff0000u);
}

// ---------------- hierarchical CSR build ----------------

__global__ __launch_bounds__(256) void coarse_hist(const int* __restrict__ dst,
                                                   int* __restrict__ ghist) {
    __shared__ int lh[NB];
    for (int i = threadIdx.x; i < NB; i += 256) lh[i] = 0;
    __syncthreads();
    int base = blockIdx.x * 4096;
#pragma unroll
    for (int j = 0; j < 16; j++) {
        int i = base + j * 256 + threadIdx.x;
        if (i < NE) atomicAdd(&lh[dst[i] >> 9], 1);
    }
    __syncthreads();
    for (int i = threadIdx.x; i < NB; i += 256)
        if (lh[i]) atomicAdd(&ghist[i], lh[i]);
}

__global__ void scan_buckets(const int* __restrict__ ghist, int* __restrict__ bucketBase,
                             int* __restrict__ gcursor, int* __restrict__ row_ptr) {
    __shared__ int A[256];
    int t = threadIdx.x;
    int v = (t < NB) ? ghist[t] : 0;
    A[t] = v;
    __syncthreads();
    for (int d = 1; d < 256; d <<= 1) {
        int x = A[t];
        int y = (t >= d) ? A[t - d] : 0;
        __syncthreads();
        A[t] = x + y;
        __syncthreads();
    }
    int excl = (t == 0) ? 0 : A[t - 1];
    if (t < NB) { bucketBase[t] = excl; gcursor[t] = excl; }
    if (t == 0) { bucketBase[NB] = NE; row_ptr[NN] = NE; }
}

// Stage CH records in LDS ordered by coarse bucket; write contiguous runs.
// Intermediate record: x = (dstLocal(9b) << 17) | src(17b), y = val bits.
__global__ __launch_bounds__(256) void partition_kernel(const int* __restrict__ src,
                                                        const int* __restrict__ dst,
                                                        const float* __restrict__ vals,
                                                        int* __restrict__ gcursor,
                                                        int2* __restrict__ recA) {
    __shared__ int lhist[NB];
    __shared__ int lstart[NB];
    __shared__ int lcur[NB];
    __shared__ int gbase[NB];
    __shared__ int2 rec[CH];
    __shared__ unsigned short bid[CH];
    __shared__ int scanbuf[256];

    int t = threadIdx.x;
    int base = blockIdx.x * CH;
    int cnt = min(CH, NE - base);

    for (int i = t; i < NB; i += 256) lhist[i] = 0;
    __syncthreads();
#pragma unroll
    for (int j = 0; j < CH / 256; j++) {
        int i = j * 256 + t;
        if (i < cnt) atomicAdd(&lhist[dst[base + i] >> 9], 1);
    }
    __syncthreads();
    {   // exclusive scan of lhist -> lstart; reserve global runs
        int v = (t < NB) ? lhist[t] : 0;
        scanbuf[t] = v;
        __syncthreads();
        for (int d = 1; d < 256; d <<= 1) {
            int x = scanbuf[t];
            int y = (t >= d) ? scanbuf[t - d] : 0;
            __syncthreads();
            scanbuf[t] = x + y;
            __syncthreads();
        }
        if (t < NB) {
            int excl = (t == 0) ? 0 : scanbuf[t - 1];
            lstart[t] = excl;
            lcur[t] = excl;
            gbase[t] = lhist[t] ? atomicAdd(&gcursor[t], lhist[t]) : 0;
        }
    }
    __syncthreads();
#pragma unroll
    for (int j = 0; j < CH / 256; j++) {
        int i = j * 256 + t;
        if (i < cnt) {
            int d = dst[base + i];
            int b = d >> 9;
            int slot = atomicAdd(&lcur[b], 1);
            rec[slot] = make_int2(((d & 511) << 17) | src[base + i],
                                  __builtin_bit_cast(int, vals[base + i]));
            bid[slot] = (unsigned short)b;
        }
    }
    __syncthreads();
    for (int i = t; i < cnt; i += 256) {
        int b = bid[i];
        recA[gbase[b] + (i - lstart[b])] = rec[i];
    }
}

// One block per bucket: exact per-node CSR inside an L2-resident window.
__global__ __launch_bounds__(256) void csr_kernel(const int2* __restrict__ recA,
                                                  const int* __restrict__ bucketBase,
                                                  int* __restrict__ row_ptr,
                                                  int2* __restrict__ edges) {
    __shared__ int lh[B_NODES];
    __shared__ int lcur[B_NODES];
    __shared__ int wsum[4];
    int t = threadIdx.x;
    int b = blockIdx.x;
    int e0 = bucketBase[b], e1 = bucketBase[b + 1];

    for (int i = t; i < B_NODES; i += 256) lh[i] = 0;
    __syncthreads();
    for (int e = e0 + t; e < e1; e += 256)
        atomicAdd(&lh[(unsigned)recA[e].x >> 17], 1);
    __syncthreads();

    // exclusive scan of lh[512]: 2 elems/thread
    int a0 = lh[2 * t], a1 = lh[2 * t + 1];
    int s = a0 + a1;
    int lane = t & 63, wid = t >> 6;
    int si = s;
    for (int off = 1; off < 64; off <<= 1) {
        int y = __shfl_up(si, off, 64);
        if (lane >= off) si += y;
    }
    if (lane == 63) wsum[wid] = si;
    __syncthreads();
    int wpre = 0;
    for (int w = 0; w < wid; w++) wpre += wsum[w];
    int texcl = wpre + si - s;
    lh[2 * t] = texcl;
    lh[2 * t + 1] = texcl + a0;
    lcur[2 * t] = texcl;
    lcur[2 * t + 1] = texcl + a0;
    __syncthreads();

    int nodeBase = b * B_NODES;
    for (int n = t; n < B_NODES; n += 256) {
        int node = nodeBase + n;
        if (node < NN) row_ptr[node] = e0 + lh[n];
    }
    for (int e = e0 + t; e < e1; e += 256) {
        int2 r = recA[e];
        int dl = (unsigned)r.x >> 17;
        int p = atomicAdd(&lcur[dl], 1);
        edges[e0 + p] = make_int2(r.x & 0x1FFFF, r.y);
    }
}

// ---------------- W fragment pre-arrangement ----------------

__global__ __launch_bounds__(256) void prep_w_kernel(const float* __restrict__ W1,
                                                     const float* __restrict__ W2,
                                                     unsigned short* __restrict__ W1b,
                                                     unsigned short* __restrict__ W2b) {
    int id = blockIdx.x * 256 + threadIdx.x;  // 0..3071
    if (id < 2048) {
        int f = id >> 6, l = id & 63;
        int t = f >> 2, kb = f & 3;
        int k0 = kb * 32 + (l >> 4) * 8, n = t * 16 + (l & 15);
        unsigned short tmp[8];
#pragma unroll
        for (int j = 0; j < 8; j++) tmp[j] = bf16one(W1[(k0 + j) * 128 + n]);
        *(s16x8*)(W1b + (size_t)id * 8) = *(const s16x8*)tmp;
    } else if (id < 3072) {
        int id2 = id - 2048;
        int f = id2 >> 6, l = id2 & 63;
        int t = f >> 2, kb = f & 3;
        int k0 = kb * 32 + (l >> 4) * 8, n = t * 16 + (l & 15);
        unsigned short tmp[8];
#pragma unroll
        for (int j = 0; j < 8; j++) tmp[j] = bf16one(W2[(k0 + j) * 64 + n]);
        *(s16x8*)(W2b + (size_t)id2 * 8) = *(const s16x8*)tmp;
    }
}

// ---------------- MFMA GEMM ----------------

template <int NT, bool A_BF16>
__global__ __launch_bounds__(256) void gemm_mfma_kernel(const float* __restrict__ Af,
                                                        const unsigned short* __restrict__ Ab,
                                                        const unsigned short* __restrict__ Wb,
                                                        const float* __restrict__ bias,
                                                        unsigned short* __restrict__ C) {
    constexpr int NC = NT * 16;
    int lane = threadIdx.x & 63;
    int wave = (blockIdx.x * 256 + threadIdx.x) >> 6;
    int nwaves = gridDim.x * 4;
    int col = lane & 15;
    int quad = lane >> 4;

    s16x8 bF[NT][4];
#pragma unroll
    for (int t = 0; t < NT; t++)
#pragma unroll
        for (int kb = 0; kb < 4; kb++)
            bF[t][kb] = *(const s16x8*)(Wb + (size_t)((t * 4 + kb) * 64 + lane) * 8);

    const int mtiles = NN / 16;
    for (int mt = wave; mt < mtiles; mt += nwaves) {
        int row = mt * 16 + col;
        s16x8 aF[4];
        if (!A_BF16) {
#pragma unroll
            for (int kb = 0; kb < 4; kb++) {
                const float4* px = (const float4*)(Af + (size_t)row * 128 + kb * 32 + quad * 8);
                float4 f0 = px[0], f1 = px[1];
                unsigned u[4];
                u[0] = bf16pack(f0.x, f0.y);
                u[1] = bf16pack(f0.z, f0.w);
                u[2] = bf16pack(f1.x, f1.y);
                u[3] = bf16pack(f1.z, f1.w);
                aF[kb] = __builtin_bit_cast(s16x8, *(const uint4*)u);
            }
        } else {
#pragma unroll
            for (int kb = 0; kb < 4; kb++) {
                uint4 u = *(const uint4*)(Ab + (size_t)row * 128 + kb * 32 + quad * 8);
                const float4* pb = (const float4*)(bias + kb * 32 + quad * 8);
                float4 b0 = pb[0], b1 = pb[1];
                unsigned r[4];
                r[0] = bf16pack(fmaxf(bf16lo(u.x) + b0.x, 0.f), fmaxf(bf16hi(u.x) + b0.y, 0.f));
                r[1] = bf16pack(fmaxf(bf16lo(u.y) + b0.z, 0.f), fmaxf(bf16hi(u.y) + b0.w, 0.f));
                r[2] = bf16pack(fmaxf(bf16lo(u.z) + b1.x, 0.f), fmaxf(bf16hi(u.z) + b1.y, 0.f));
                r[3] = bf16pack(fmaxf(bf16lo(u.w) + b1.z, 0.f), fmaxf(bf16hi(u.w) + b1.w, 0.f));
                aF[kb] = __builtin_bit_cast(s16x8, *(const uint4*)r);
            }
        }

        f32x4 acc[NT];
#pragma unroll
        for (int t = 0; t < NT; t++) acc[t] = (f32x4){0.f, 0.f, 0.f, 0.f};
#pragma unroll
        for (int kb = 0; kb < 4; kb++)
#pragma unroll
            for (int t = 0; t < NT; t++)
                acc[t] = __builtin_amdgcn_mfma_f32_16x16x32_bf16(aF[kb], bF[t][kb], acc[t], 0, 0, 0);

        int crow = mt * 16 + quad * 4;
#pragma unroll
        for (int t = 0; t < NT; t++)
#pragma unroll
            for (int r = 0; r < 4; r++)
                C[(size_t)(crow + r) * NC + t * 16 + col] = bf16one(acc[t][r]);
    }
}

// ---------------- SpMM (gather by dst via CSR), bf16 operand ----------------

__global__ __launch_bounds__(256) void spmm128_kernel(const int* __restrict__ row_ptr,
                                                      const int2* __restrict__ E,
                                                      const unsigned* __restrict__ X,  // bf16x2/row
                                                      unsigned* __restrict__ Yb) {     // bf16x2/row
    int wid = threadIdx.x >> 6;
    int lane = threadIdx.x & 63;
    int node = blockIdx.x * 4 + wid;
    if (node >= NN) return;
    int e0 = __builtin_amdgcn_readfirstlane(row_ptr[node]);
    int e1 = __builtin_amdgcn_readfirstlane(row_ptr[node + 1]);
    float ax = 0.f, ay = 0.f;
    int e = e0;
    for (; e + 8 <= e1; e += 8) {
        int2 ed[8];
#pragma unroll
        for (int j = 0; j < 8; j++) ed[j] = E[e + j];
        unsigned u[8];
#pragma unroll
        for (int j = 0; j < 8; j++) u[j] = X[(size_t)ed[j].x * 64 + lane];
#pragma unroll
        for (int j = 0; j < 8; j++) {
            float v = __builtin_bit_cast(float, ed[j].y);
            ax += v * bf16lo(u[j]);
            ay += v * bf16hi(u[j]);
        }
    }
    for (; e < e1; ++e) {
        int2 ed = E[e];
        float v = __builtin_bit_cast(float, ed.y);
        unsigned u = X[(size_t)ed.x * 64 + lane];
        ax += v * bf16lo(u);
        ay += v * bf16hi(u);
    }
    Yb[(size_t)node * 64 + lane] = bf16pack(ax, ay);
}

__global__ __launch_bounds__(256) void spmm64_kernel(const int* __restrict__ row_ptr,
                                                     const int2* __restrict__ E,
                                                     const unsigned short* __restrict__ X,
                                                     const float* __restrict__ b2,
                                                     float* __restrict__ out) {
    int wid = threadIdx.x >> 6;
    int lane = threadIdx.x & 63;
    int node = blockIdx.x * 4 + wid;
    if (node >= NN) return;
    int e0 = __builtin_amdgcn_readfirstlane(row_ptr[node]);
    int e1 = __builtin_amdgcn_readfirstlane(row_ptr[node + 1]);
    float acc = b2[lane];
    int e = e0;
    for (; e + 8 <= e1; e += 8) {
        int2 ed[8];
#pragma unroll
        for (int j = 0; j < 8; j++) ed[j] = E[e + j];
        unsigned short u[8];
#pragma unroll
        for (int j = 0; j < 8; j++) u[j] = X[(size_t)ed[j].x * 64 + lane];
#pragma unroll
        for (int j = 0; j < 8; j++)
            acc += __builtin_bit_cast(float, ed[j].y) *
                   __builtin_bit_cast(float, (unsigned)u[j] << 16);
    }
    for (; e < e1; ++e) {
        int2 ed = E[e];
        acc += __builtin_bit_cast(float, ed.y) *
               __builtin_bit_cast(float, (unsigned)X[(size_t)ed.x * 64 + lane] << 16);
    }
    out[(size_t)node * 64 + lane] = acc;
}

// ---------------- launch ----------------

extern "C" void kernel_launch(void* const* d_in, const int* in_sizes, int n_in,
                              void* d_out, int out_size, void* d_ws, size_t ws_size,
                              hipStream_t stream) {
    const float* x        = (const float*)d_in[0];
    const int*   edge_src = (const int*)d_in[1];
    const int*   edge_dst = (const int*)d_in[2];
    const float* edge_val = (const float*)d_in[3];
    const float* W1       = (const float*)d_in[4];
    const float* b1       = (const float*)d_in[5];
    const float* W2       = (const float*)d_in[6];
    const float* b2       = (const float*)d_in[7];
    float* out = (float*)d_out;

    char* p = (char*)d_ws;
    auto alloc = [&](size_t bytes) {
        char* q = p;
        p += (bytes + 255) & ~(size_t)255;
        return (void*)q;
    };
    unsigned short* t1  = (unsigned short*)alloc((size_t)NN * 128 * 2);  // xW1 bf16; reused as t2
    unsigned short* y1b = (unsigned short*)alloc((size_t)NN * 128 * 2);  // spmm(t1) bf16
    int2* recA          = (int2*)alloc((size_t)NE * 8);   // bucket-partitioned records
    int2* edges         = (int2*)alloc((size_t)NE * 8);   // final CSR records
    int*  ghist         = (int*)alloc((size_t)NB * 4);
    int*  bucketBase    = (int*)alloc((size_t)(NB + 1) * 4);
    int*  gcursor       = (int*)alloc((size_t)NB * 4);
    int*  row_ptr       = (int*)alloc((size_t)(NN + 1) * 4);
    unsigned short* W1b = (unsigned short*)alloc(2048 * 8 * 2);
    unsigned short* W2b = (unsigned short*)alloc(1024 * 8 * 2);
    unsigned short* t2 = t1;  // t1 dead after spmm128

    (void)hipMemsetAsync(ghist, 0, (size_t)NB * 4, stream);
    prep_w_kernel<<<12, 256, 0, stream>>>(W1, W2, W1b, W2b);
    coarse_hist<<<(NE + 4095) / 4096, 256, 0, stream>>>(edge_dst, ghist);
    scan_buckets<<<1, 256, 0, stream>>>(ghist, bucketBase, gcursor, row_ptr);
    partition_kernel<<<NCHUNK, 256, 0, stream>>>(edge_src, edge_dst, edge_val, gcursor, recA);
    csr_kernel<<<NB, 256, 0, stream>>>(recA, bucketBase, row_ptr, edges);

    // t1 = bf16(x) @ W1
    gemm_mfma_kernel<8, false><<<256, 256, 0, stream>>>(x, nullptr, W1b, nullptr, t1);
    // y1b = spmm(t1)  (bf16 out)
    spmm128_kernel<<<(NN + 3) / 4, 256, 0, stream>>>(row_ptr, edges, (const unsigned*)t1, (unsigned*)y1b);
    // t2 = relu(y1b + b1) @ W2
    gemm_mfma_kernel<4, true><<<256, 256, 0, stream>>>(nullptr, y1b, W2b, b1, t2);
    // out = spmm(t2) + b2
    spmm64_kernel<<<(NN + 3) / 4, 256, 0, stream>>>(row_ptr, edges, t2, b2, out);
}

// Round 6
// 306.395 us; speedup vs baseline: 2.3643x; 1.0427x over previous
//
#include <hip/hip_runtime.h>

#define NN 100000
#define NE 1600000
// dims: IN=128, HID=128, LAT=64. NN % 16 == 0.

#define B_NODES 512      // nodes per coarse bucket (2^9)
#define NB 196           // ceil(NN / B_NODES)
#define CH 4096          // edges per partition block (LDS ~44 KB -> 3 blocks/CU)
#define NCHUNK 391       // ceil(NE / CH)

typedef __attribute__((ext_vector_type(4))) float f32x4;
typedef __attribute__((ext_vector_type(8))) short s16x8;

// ---------------- helpers ----------------

__device__ __forceinline__ unsigned bf16pack(float a, float b) {
    unsigned ua = __builtin_bit_cast(unsigned, a);
    unsigned ub = __builtin_bit_cast(unsigned, b);
    ua = (ua + 0x7fffu + ((ua >> 16) & 1u)) >> 16;   // RNE
    ub = (ub + 0x7fffu + ((ub >> 16) & 1u)) >> 16;
    return ua | (ub << 16);
}
__device__ __forceinline__ unsigned short bf16one(float a) {
    unsigned ua = __builtin_bit_cast(unsigned, a);
    return (unsigned short)((ua + 0x7fffu + ((ua >> 16) & 1u)) >> 16);
}
__device__ __forceinline__ float bf16lo(unsigned u) {
    return __builtin_bit_cast(float, u << 16);
}
__device__ __forceinline__ float bf16hi(unsigned u) {
    return __builtin_bit_cast(float, u & 0xffff0000u);
}

// ---------------- hierarchical CSR build ----------------

__global__ __launch_bounds__(256) void coarse_hist(const int* __restrict__ dst,
                                                   int* __restrict__ ghist) {
    __shared__ int lh[NB];
    for (int i = threadIdx.x; i < NB; i += 256) lh[i] = 0;
    __syncthreads();
    int base = blockIdx.x * 4096;
#pragma unroll
    for (int j = 0; j < 16; j++) {
        int i = base + j * 256 + threadIdx.x;
        if (i < NE) atomicAdd(&lh[dst[i] >> 9], 1);
    }
    __syncthreads();
    for (int i = threadIdx.x; i < NB; i += 256)
        if (lh[i]) atomicAdd(&ghist[i], lh[i]);
}

__global__ void scan_buckets(const int* __restrict__ ghist, int* __restrict__ bucketBase,
                             int* __restrict__ gcursor, int* __restrict__ row_ptr) {
    __shared__ int A[256];
    int t = threadIdx.x;
    int v = (t < NB) ? ghist[t] : 0;
    A[t] = v;
    __syncthreads();
    for (int d = 1; d < 256; d <<= 1) {
        int x = A[t];
        int y = (t >= d) ? A[t - d] : 0;
        __syncthreads();
        A[t] = x + y;
        __syncthreads();
    }
    int excl = (t == 0) ? 0 : A[t - 1];
    if (t < NB) { bucketBase[t] = excl; gcursor[t] = excl; }
    if (t == 0) { bucketBase[NB] = NE; row_ptr[NN] = NE; }
}

// Stage CH records in LDS ordered by coarse bucket; write contiguous runs.
// Intermediate record: x = (dstLocal(9b) << 17) | src(17b), y = val bits.
__global__ __launch_bounds__(256) void partition_kernel(const int* __restrict__ src,
                                                        const int* __restrict__ dst,
                                                        const float* __restrict__ vals,
                                                        int* __restrict__ gcursor,
                                                        int2* __restrict__ recA) {
    __shared__ int lhist[NB];
    __shared__ int lstart[NB];
    __shared__ int lcur[NB];
    __shared__ int gbase[NB];
    __shared__ int2 rec[CH];
    __shared__ unsigned short bid[CH];
    __shared__ int scanbuf[256];

    int t = threadIdx.x;
    int base = blockIdx.x * CH;
    int cnt = min(CH, NE - base);

    for (int i = t; i < NB; i += 256) lhist[i] = 0;
    __syncthreads();
#pragma unroll
    for (int j = 0; j < CH / 256; j++) {
        int i = j * 256 + t;
        if (i < cnt) atomicAdd(&lhist[dst[base + i] >> 9], 1);
    }
    __syncthreads();
    {   // exclusive scan of lhist -> lstart; reserve global runs
        int v = (t < NB) ? lhist[t] : 0;
        scanbuf[t] = v;
        __syncthreads();
        for (int d = 1; d < 256; d <<= 1) {
            int x = scanbuf[t];
            int y = (t >= d) ? scanbuf[t - d] : 0;
            __syncthreads();
            scanbuf[t] = x + y;
            __syncthreads();
        }
        if (t < NB) {
            int excl = (t == 0) ? 0 : scanbuf[t - 1];
            lstart[t] = excl;
            lcur[t] = excl;
            gbase[t] = lhist[t] ? atomicAdd(&gcursor[t], lhist[t]) : 0;
        }
    }
    __syncthreads();
#pragma unroll
    for (int j = 0; j < CH / 256; j++) {
        int i = j * 256 + t;
        if (i < cnt) {
            int d = dst[base + i];
            int b = d >> 9;
            int slot = atomicAdd(&lcur[b], 1);
            rec[slot] = make_int2(((d & 511) << 17) | src[base + i],
                                  __builtin_bit_cast(int, vals[base + i]));
            bid[slot] = (unsigned short)b;
        }
    }
    __syncthreads();
    for (int i = t; i < cnt; i += 256) {
        int b = bid[i];
        recA[gbase[b] + (i - lstart[b])] = rec[i];
    }
}

// One block per bucket: exact per-node CSR inside an L2-resident window.
__global__ __launch_bounds__(256) void csr_kernel(const int2* __restrict__ recA,
                                                  const int* __restrict__ bucketBase,
                                                  int* __restrict__ row_ptr,
                                                  int2* __restrict__ edges) {
    __shared__ int lh[B_NODES];
    __shared__ int lcur[B_NODES];
    __shared__ int wsum[4];
    int t = threadIdx.x;
    int b = blockIdx.x;
    int e0 = bucketBase[b], e1 = bucketBase[b + 1];

    for (int i = t; i < B_NODES; i += 256) lh[i] = 0;
    __syncthreads();
    for (int e = e0 + t; e < e1; e += 256)
        atomicAdd(&lh[(unsigned)recA[e].x >> 17], 1);
    __syncthreads();

    // exclusive scan of lh[512]: 2 elems/thread
    int a0 = lh[2 * t], a1 = lh[2 * t + 1];
    int s = a0 + a1;
    int lane = t & 63, wid = t >> 6;
    int si = s;
    for (int off = 1; off < 64; off <<= 1) {
        int y = __shfl_up(si, off, 64);
        if (lane >= off) si += y;
    }
    if (lane == 63) wsum[wid] = si;
    __syncthreads();
    int wpre = 0;
    for (int w = 0; w < wid; w++) wpre += wsum[w];
    int texcl = wpre + si - s;
    lh[2 * t] = texcl;
    lh[2 * t + 1] = texcl + a0;
    lcur[2 * t] = texcl;
    lcur[2 * t + 1] = texcl + a0;
    __syncthreads();

    int nodeBase = b * B_NODES;
    for (int n = t; n < B_NODES; n += 256) {
        int node = nodeBase + n;
        if (node < NN) row_ptr[node] = e0 + lh[n];
    }
    for (int e = e0 + t; e < e1; e += 256) {
        int2 r = recA[e];
        int dl = (unsigned)r.x >> 17;
        int p = atomicAdd(&lcur[dl], 1);
        edges[e0 + p] = make_int2(r.x & 0x1FFFF, r.y);
    }
}

// ---------------- W fragment pre-arrangement ----------------

__global__ __launch_bounds__(256) void prep_w_kernel(const float* __restrict__ W1,
                                                     const float* __restrict__ W2,
                                                     unsigned short* __restrict__ W1b,
                                                     unsigned short* __restrict__ W2b) {
    int id = blockIdx.x * 256 + threadIdx.x;  // 0..3071
    if (id < 2048) {
        int f = id >> 6, l = id & 63;
        int t = f >> 2, kb = f & 3;
        int k0 = kb * 32 + (l >> 4) * 8, n = t * 16 + (l & 15);
        unsigned short tmp[8];
#pragma unroll
        for (int j = 0; j < 8; j++) tmp[j] = bf16one(W1[(k0 + j) * 128 + n]);
        *(s16x8*)(W1b + (size_t)id * 8) = *(const s16x8*)tmp;
    } else if (id < 3072) {
        int id2 = id - 2048;
        int f = id2 >> 6, l = id2 & 63;
        int t = f >> 2, kb = f & 3;
        int k0 = kb * 32 + (l >> 4) * 8, n = t * 16 + (l & 15);
        unsigned short tmp[8];
#pragma unroll
        for (int j = 0; j < 8; j++) tmp[j] = bf16one(W2[(k0 + j) * 64 + n]);
        *(s16x8*)(W2b + (size_t)id2 * 8) = *(const s16x8*)tmp;
    }
}

// ---------------- MFMA GEMM ----------------

template <int NT, bool A_BF16>
__global__ __launch_bounds__(256) void gemm_mfma_kernel(const float* __restrict__ Af,
                                                        const unsigned short* __restrict__ Ab,
                                                        const unsigned short* __restrict__ Wb,
                                                        const float* __restrict__ bias,
                                                        unsigned short* __restrict__ C) {
    constexpr int NC = NT * 16;
    int lane = threadIdx.x & 63;
    int wave = (blockIdx.x * 256 + threadIdx.x) >> 6;
    int nwaves = gridDim.x * 4;
    int col = lane & 15;
    int quad = lane >> 4;

    s16x8 bF[NT][4];
#pragma unroll
    for (int t = 0; t < NT; t++)
#pragma unroll
        for (int kb = 0; kb < 4; kb++)
            bF[t][kb] = *(const s16x8*)(Wb + (size_t)((t * 4 + kb) * 64 + lane) * 8);

    const int mtiles = NN / 16;
    for (int mt = wave; mt < mtiles; mt += nwaves) {
        int row = mt * 16 + col;
        s16x8 aF[4];
        if (!A_BF16) {
#pragma unroll
            for (int kb = 0; kb < 4; kb++) {
                const float4* px = (const float4*)(Af + (size_t)row * 128 + kb * 32 + quad * 8);
                float4 f0 = px[0], f1 = px[1];
                unsigned u[4];
                u[0] = bf16pack(f0.x, f0.y);
                u[1] = bf16pack(f0.z, f0.w);
                u[2] = bf16pack(f1.x, f1.y);
                u[3] = bf16pack(f1.z, f1.w);
                aF[kb] = __builtin_bit_cast(s16x8, *(const uint4*)u);
            }
        } else {
#pragma unroll
            for (int kb = 0; kb < 4; kb++) {
                uint4 u = *(const uint4*)(Ab + (size_t)row * 128 + kb * 32 + quad * 8);
                const float4* pb = (const float4*)(bias + kb * 32 + quad * 8);
                float4 b0 = pb[0], b1 = pb[1];
                unsigned r[4];
                r[0] = bf16pack(fmaxf(bf16lo(u.x) + b0.x, 0.f), fmaxf(bf16hi(u.x) + b0.y, 0.f));
                r[1] = bf16pack(fmaxf(bf16lo(u.y) + b0.z, 0.f), fmaxf(bf16hi(u.y) + b0.w, 0.f));
                r[2] = bf16pack(fmaxf(bf16lo(u.z) + b1.x, 0.f), fmaxf(bf16hi(u.z) + b1.y, 0.f));
                r[3] = bf16pack(fmaxf(bf16lo(u.w) + b1.z, 0.f), fmaxf(bf16hi(u.w) + b1.w, 0.f));
                aF[kb] = __builtin_bit_cast(s16x8, *(const uint4*)r);
            }
        }

        f32x4 acc[NT];
#pragma unroll
        for (int t = 0; t < NT; t++) acc[t] = (f32x4){0.f, 0.f, 0.f, 0.f};
#pragma unroll
        for (int kb = 0; kb < 4; kb++)
#pragma unroll
            for (int t = 0; t < NT; t++)
                acc[t] = __builtin_amdgcn_mfma_f32_16x16x32_bf16(aF[kb], bF[t][kb], acc[t], 0, 0, 0);

        int crow = mt * 16 + quad * 4;
#pragma unroll
        for (int t = 0; t < NT; t++)
#pragma unroll
            for (int r = 0; r < 4; r++)
                C[(size_t)(crow + r) * NC + t * 16 + col] = bf16one(acc[t][r]);
    }
}

// ---------------- SpMM (gather by dst via CSR), bf16 operand ----------------
// D=128 (256B rows): 32 lanes x 8B cover a row -> 2 edges per gather instr.
// Lanes 0-31 = even edge of pair, lanes 32-63 = odd edge. Lane owns dims 4g..4g+3.

__global__ __launch_bounds__(256) void spmm128_kernel(const int* __restrict__ row_ptr,
                                                      const int2* __restrict__ E,
                                                      const uint2* __restrict__ X2,  // 32 granules/row
                                                      uint2* __restrict__ Yb) {      // 32 granules/row
    int wid = threadIdx.x >> 6;
    int lane = threadIdx.x & 63;
    int node = blockIdx.x * 4 + wid;
    if (node >= NN) return;
    int e0 = __builtin_amdgcn_readfirstlane(row_ptr[node]);
    int e1 = __builtin_amdgcn_readfirstlane(row_ptr[node + 1]);
    int half = lane >> 5;
    int g = lane & 31;
    float a0 = 0.f, a1 = 0.f, a2 = 0.f, a3 = 0.f;
    int e = e0;
    for (; e + 16 <= e1; e += 16) {
        int2 rec = E[e + (lane & 15)];  // 16 records, replicated across quarters
        uint2 u[8];
        float v[8];
#pragma unroll
        for (int j = 0; j < 8; j++) {
            int sel = 2 * j + half;
            int sv = __shfl(rec.x, sel, 64);
            v[j] = __builtin_bit_cast(float, __shfl(rec.y, sel, 64));
            u[j] = X2[(size_t)sv * 32 + g];
        }
#pragma unroll
        for (int j = 0; j < 8; j++) {
            a0 += v[j] * bf16lo(u[j].x);
            a1 += v[j] * bf16hi(u[j].x);
            a2 += v[j] * bf16lo(u[j].y);
            a3 += v[j] * bf16hi(u[j].y);
        }
    }
    int rem = e1 - e;
    if (rem > 0) {
        int2 rec = E[e + min(lane & 15, rem - 1)];
        int np = (rem + 1) >> 1;
        for (int j = 0; j < np; j++) {
            int idx = 2 * j + half;
            int sel = min(idx, rem - 1);
            int sv = __shfl(rec.x, sel, 64);
            float vv = __builtin_bit_cast(float, __shfl(rec.y, sel, 64));
            if (idx >= rem) vv = 0.f;
            uint2 u = X2[(size_t)sv * 32 + g];
            a0 += vv * bf16lo(u.x);
            a1 += vv * bf16hi(u.x);
            a2 += vv * bf16lo(u.y);
            a3 += vv * bf16hi(u.y);
        }
    }
    // combine halves (partner = lane ^ 32)
    a0 += __shfl(a0, lane ^ 32, 64);
    a1 += __shfl(a1, lane ^ 32, 64);
    a2 += __shfl(a2, lane ^ 32, 64);
    a3 += __shfl(a3, lane ^ 32, 64);
    if (half == 0)
        Yb[(size_t)node * 32 + g] = make_uint2(bf16pack(a0, a1), bf16pack(a2, a3));
}

// D=64 (128B rows): 16 lanes x 8B cover a row -> 4 edges per gather instr.
// Group grp = lane>>4 handles edge 4j+grp. fp32 output with bias.

__global__ __launch_bounds__(256) void spmm64_kernel(const int* __restrict__ row_ptr,
                                                     const int2* __restrict__ E,
                                                     const uint2* __restrict__ X2,  // 16 granules/row
                                                     const float* __restrict__ b2,
                                                     float* __restrict__ out) {
    int wid = threadIdx.x >> 6;
    int lane = threadIdx.x & 63;
    int node = blockIdx.x * 4 + wid;
    if (node >= NN) return;
    int e0 = __builtin_amdgcn_readfirstlane(row_ptr[node]);
    int e1 = __builtin_amdgcn_readfirstlane(row_ptr[node + 1]);
    int grp = lane >> 4;
    int g = lane & 15;
    float a0 = 0.f, a1 = 0.f, a2 = 0.f, a3 = 0.f;
    int e = e0;
    for (; e + 32 <= e1; e += 32) {
        int2 rec = E[e + (lane & 31)];  // 32 records, replicated across halves
        uint2 u[8];
        float v[8];
#pragma unroll
        for (int j = 0; j < 8; j++) {
            int sel = 4 * j + grp;
            int sv = __shfl(rec.x, sel, 64);
            v[j] = __builtin_bit_cast(float, __shfl(rec.y, sel, 64));
            u[j] = X2[(size_t)sv * 16 + g];
        }
#pragma unroll
        for (int j = 0; j < 8; j++) {
            a0 += v[j] * bf16lo(u[j].x);
            a1 += v[j] * bf16hi(u[j].x);
            a2 += v[j] * bf16lo(u[j].y);
            a3 += v[j] * bf16hi(u[j].y);
        }
    }
    int rem = e1 - e;
    if (rem > 0) {
        int2 rec = E[e + min(lane & 31, rem - 1)];
        int np = (rem + 3) >> 2;
        for (int j = 0; j < np; j++) {
            int idx = 4 * j + grp;
            int sel = min(idx, rem - 1);
            int sv = __shfl(rec.x, sel, 64);
            float vv = __builtin_bit_cast(float, __shfl(rec.y, sel, 64));
            if (idx >= rem) vv = 0.f;
            uint2 u = X2[(size_t)sv * 16 + g];
            a0 += vv * bf16lo(u.x);
            a1 += vv * bf16hi(u.x);
            a2 += vv * bf16lo(u.y);
            a3 += vv * bf16hi(u.y);
        }
    }
    // reduce across 4 groups (stride-16 butterfly)
    a0 += __shfl(a0, lane ^ 16, 64); a0 += __shfl(a0, lane ^ 32, 64);
    a1 += __shfl(a1, lane ^ 16, 64); a1 += __shfl(a1, lane ^ 32, 64);
    a2 += __shfl(a2, lane ^ 16, 64); a2 += __shfl(a2, lane ^ 32, 64);
    a3 += __shfl(a3, lane ^ 16, 64); a3 += __shfl(a3, lane ^ 32, 64);
    if (grp == 0) {
        const float4 bb = ((const float4*)b2)[g];
        ((float4*)out)[(size_t)node * 16 + g] =
            make_float4(a0 + bb.x, a1 + bb.y, a2 + bb.z, a3 + bb.w);
    }
}

// ---------------- launch ----------------

extern "C" void kernel_launch(void* const* d_in, const int* in_sizes, int n_in,
                              void* d_out, int out_size, void* d_ws, size_t ws_size,
                              hipStream_t stream) {
    const float* x        = (const float*)d_in[0];
    const int*   edge_src = (const int*)d_in[1];
    const int*   edge_dst = (const int*)d_in[2];
    const float* edge_val = (const float*)d_in[3];
    const float* W1       = (const float*)d_in[4];
    const float* b1       = (const float*)d_in[5];
    const float* W2       = (const float*)d_in[6];
    const float* b2       = (const float*)d_in[7];
    float* out = (float*)d_out;

    char* p = (char*)d_ws;
    auto alloc = [&](size_t bytes) {
        char* q = p;
        p += (bytes + 255) & ~(size_t)255;
        return (void*)q;
    };
    unsigned short* t1  = (unsigned short*)alloc((size_t)NN * 128 * 2);  // xW1 bf16; reused as t2
    unsigned short* y1b = (unsigned short*)alloc((size_t)NN * 128 * 2);  // spmm(t1) bf16
    int2* recA          = (int2*)alloc((size_t)NE * 8);   // bucket-partitioned records
    int2* edges         = (int2*)alloc((size_t)NE * 8);   // final CSR records
    int*  ghist         = (int*)alloc((size_t)NB * 4);
    int*  bucketBase    = (int*)alloc((size_t)(NB + 1) * 4);
    int*  gcursor       = (int*)alloc((size_t)NB * 4);
    int*  row_ptr       = (int*)alloc((size_t)(NN + 1) * 4);
    unsigned short* W1b = (unsigned short*)alloc(2048 * 8 * 2);
    unsigned short* W2b = (unsigned short*)alloc(1024 * 8 * 2);
    unsigned short* t2 = t1;  // t1 dead after spmm128

    (void)hipMemsetAsync(ghist, 0, (size_t)NB * 4, stream);
    prep_w_kernel<<<12, 256, 0, stream>>>(W1, W2, W1b, W2b);
    coarse_hist<<<(NE + 4095) / 4096, 256, 0, stream>>>(edge_dst, ghist);
    scan_buckets<<<1, 256, 0, stream>>>(ghist, bucketBase, gcursor, row_ptr);
    partition_kernel<<<NCHUNK, 256, 0, stream>>>(edge_src, edge_dst, edge_val, gcursor, recA);
    csr_kernel<<<NB, 256, 0, stream>>>(recA, bucketBase, row_ptr, edges);

    // t1 = bf16(x) @ W1
    gemm_mfma_kernel<8, false><<<256, 256, 0, stream>>>(x, nullptr, W1b, nullptr, t1);
    // y1b = spmm(t1)  (bf16 out)
    spmm128_kernel<<<(NN + 3) / 4, 256, 0, stream>>>(row_ptr, edges, (const uint2*)t1, (uint2*)y1b);
    // t2 = relu(y1b + b1) @ W2
    gemm_mfma_kernel<4, true><<<256, 256, 0, stream>>>(nullptr, y1b, W2b, b1, t2);
    // out = spmm(t2) + b2
    spmm64_kernel<<<(NN + 3) / 4, 256, 0, stream>>>(row_ptr, edges, (const uint2*)t2, b2, out);
}

// Round 7
// 266.478 us; speedup vs baseline: 2.7184x; 1.1498x over previous
//
#include <hip/hip_runtime.h>

#define NN 100000
#define NE 1600000
// dims: IN=128, HID=128, LAT=64. NN % 16 == 0.

#define B_NODES 512      // nodes per coarse bucket (2^9)
#define NB 196           // ceil(NN / B_NODES)
#define CH 4096          // edges per partition block
#define NCHUNK 391       // ceil(NE / CH)

typedef __attribute__((ext_vector_type(4))) float f32x4;
typedef __attribute__((ext_vector_type(2))) float f32x2;
typedef __attribute__((ext_vector_type(8))) short s16x8;

// ---------------- helpers ----------------

__device__ __forceinline__ unsigned bf16pack(float a, float b) {
    unsigned ua = __builtin_bit_cast(unsigned, a);
    unsigned ub = __builtin_bit_cast(unsigned, b);
    ua = (ua + 0x7fffu + ((ua >> 16) & 1u)) >> 16;   // RNE
    ub = (ub + 0x7fffu + ((ub >> 16) & 1u)) >> 16;
    return ua | (ub << 16);
}
__device__ __forceinline__ unsigned short bf16one(float a) {
    unsigned ua = __builtin_bit_cast(unsigned, a);
    return (unsigned short)((ua + 0x7fffu + ((ua >> 16) & 1u)) >> 16);
}
__device__ __forceinline__ float bf16lo(unsigned u) {
    return __builtin_bit_cast(float, u << 16);
}
__device__ __forceinline__ float bf16hi(unsigned u) {
    return __builtin_bit_cast(float, u & 0xffff0000u);
}
__device__ __forceinline__ unsigned char fp8one(float a) {
    unsigned pk = __builtin_amdgcn_cvt_pk_fp8_f32(a, a, 0, false);
    return (unsigned char)(pk & 0xff);
}

// ---------------- hierarchical CSR build ----------------

__global__ __launch_bounds__(256) void coarse_hist(const int* __restrict__ dst,
                                                   int* __restrict__ ghist) {
    __shared__ int lh[NB];
    for (int i = threadIdx.x; i < NB; i += 256) lh[i] = 0;
    __syncthreads();
    int base = blockIdx.x * 4096;
#pragma unroll
    for (int j = 0; j < 16; j++) {
        int i = base + j * 256 + threadIdx.x;
        if (i < NE) atomicAdd(&lh[dst[i] >> 9], 1);
    }
    __syncthreads();
    for (int i = threadIdx.x; i < NB; i += 256)
        if (lh[i]) atomicAdd(&ghist[i], lh[i]);
}

__global__ void scan_buckets(const int* __restrict__ ghist, int* __restrict__ bucketBase,
                             int* __restrict__ gcursor, int* __restrict__ row_ptr) {
    __shared__ int A[256];
    int t = threadIdx.x;
    int v = (t < NB) ? ghist[t] : 0;
    A[t] = v;
    __syncthreads();
    for (int d = 1; d < 256; d <<= 1) {
        int x = A[t];
        int y = (t >= d) ? A[t - d] : 0;
        __syncthreads();
        A[t] = x + y;
        __syncthreads();
    }
    int excl = (t == 0) ? 0 : A[t - 1];
    if (t < NB) { bucketBase[t] = excl; gcursor[t] = excl; }
    if (t == 0) { bucketBase[NB] = NE; row_ptr[NN] = NE; }
}

// Stage CH records in LDS ordered by coarse bucket; write contiguous runs.
// Intermediate record: x = (dstLocal(9b) << 17) | src(17b), y = val bits.
__global__ __launch_bounds__(512) void partition_kernel(const int* __restrict__ src,
                                                        const int* __restrict__ dst,
                                                        const float* __restrict__ vals,
                                                        int* __restrict__ gcursor,
                                                        int2* __restrict__ recA) {
    __shared__ int lhist[NB];
    __shared__ int lstart[NB];
    __shared__ int lcur[NB];
    __shared__ int gbase[NB];
    __shared__ int2 rec[CH];
    __shared__ unsigned short bid[CH];
    __shared__ int scanbuf[256];

    int t = threadIdx.x;
    int base = blockIdx.x * CH;
    int cnt = min(CH, NE - base);

    for (int i = t; i < NB; i += 512) lhist[i] = 0;
    __syncthreads();
#pragma unroll
    for (int j = 0; j < CH / 512; j++) {
        int i = j * 512 + t;
        if (i < cnt) atomicAdd(&lhist[dst[base + i] >> 9], 1);
    }
    __syncthreads();
    {   // exclusive scan of lhist -> lstart (threads 0..255 drive; barriers uniform)
        int v = (t < NB) ? lhist[t] : 0;
        if (t < 256) scanbuf[t] = v;
        __syncthreads();
        for (int d = 1; d < 256; d <<= 1) {
            int x = 0, y = 0;
            if (t < 256) { x = scanbuf[t]; y = (t >= d) ? scanbuf[t - d] : 0; }
            __syncthreads();
            if (t < 256) scanbuf[t] = x + y;
            __syncthreads();
        }
        if (t < NB) {
            int excl = (t == 0) ? 0 : scanbuf[t - 1];
            lstart[t] = excl;
            lcur[t] = excl;
            gbase[t] = lhist[t] ? atomicAdd(&gcursor[t], lhist[t]) : 0;
        }
    }
    __syncthreads();
#pragma unroll
    for (int j = 0; j < CH / 512; j++) {
        int i = j * 512 + t;
        if (i < cnt) {
            int d = dst[base + i];
            int b = d >> 9;
            int slot = atomicAdd(&lcur[b], 1);
            rec[slot] = make_int2(((d & 511) << 17) | src[base + i],
                                  __builtin_bit_cast(int, vals[base + i]));
            bid[slot] = (unsigned short)b;
        }
    }
    __syncthreads();
    for (int i = t; i < cnt; i += 512) {
        int b = bid[i];
        recA[gbase[b] + (i - lstart[b])] = rec[i];
    }
}

// One block per bucket: exact per-node CSR inside an L2-resident window.
__global__ __launch_bounds__(512) void csr_kernel(const int2* __restrict__ recA,
                                                  const int* __restrict__ bucketBase,
                                                  int* __restrict__ row_ptr,
                                                  int2* __restrict__ edges) {
    __shared__ int lh[B_NODES];
    __shared__ int lcur[B_NODES];
    __shared__ int wsum[8];
    int t = threadIdx.x;
    int b = blockIdx.x;
    int e0 = bucketBase[b], e1 = bucketBase[b + 1];

    lh[t] = 0;
    __syncthreads();
    for (int e = e0 + t; e < e1; e += 512)
        atomicAdd(&lh[(unsigned)recA[e].x >> 17], 1);
    __syncthreads();

    // exclusive scan of lh[512]: 1 elem/thread, 8 waves
    int a = lh[t];
    int lane = t & 63, wid = t >> 6;
    int si = a;
    for (int off = 1; off < 64; off <<= 1) {
        int y = __shfl_up(si, off, 64);
        if (lane >= off) si += y;
    }
    if (lane == 63) wsum[wid] = si;
    __syncthreads();
    int wpre = 0;
    for (int w = 0; w < wid; w++) wpre += wsum[w];
    int excl = wpre + si - a;
    lh[t] = excl;
    lcur[t] = excl;
    __syncthreads();

    int node = b * B_NODES + t;
    if (node < NN) row_ptr[node] = e0 + lh[t];
    for (int e = e0 + t; e < e1; e += 512) {
        int2 r = recA[e];
        int dl = (unsigned)r.x >> 17;
        int p = atomicAdd(&lcur[dl], 1);
        edges[e0 + p] = make_int2(r.x & 0x1FFFF, r.y);
    }
}

// ---------------- W fragment pre-arrangement ----------------

__global__ __launch_bounds__(256) void prep_w_kernel(const float* __restrict__ W1,
                                                     const float* __restrict__ W2,
                                                     unsigned short* __restrict__ W1b,
                                                     unsigned short* __restrict__ W2b) {
    int id = blockIdx.x * 256 + threadIdx.x;  // 0..3071
    if (id < 2048) {
        int f = id >> 6, l = id & 63;
        int t = f >> 2, kb = f & 3;
        int k0 = kb * 32 + (l >> 4) * 8, n = t * 16 + (l & 15);
        unsigned short tmp[8];
#pragma unroll
        for (int j = 0; j < 8; j++) tmp[j] = bf16one(W1[(k0 + j) * 128 + n]);
        *(s16x8*)(W1b + (size_t)id * 8) = *(const s16x8*)tmp;
    } else if (id < 3072) {
        int id2 = id - 2048;
        int f = id2 >> 6, l = id2 & 63;
        int t = f >> 2, kb = f & 3;
        int k0 = kb * 32 + (l >> 4) * 8, n = t * 16 + (l & 15);
        unsigned short tmp[8];
#pragma unroll
        for (int j = 0; j < 8; j++) tmp[j] = bf16one(W2[(k0 + j) * 64 + n]);
        *(s16x8*)(W2b + (size_t)id2 * 8) = *(const s16x8*)tmp;
    }
}

// ---------------- MFMA GEMM ----------------
// OUT_FP8: C element = 1 byte fp8-e4m3, row stride NC bytes. Else bf16 shorts.

template <int NT, bool A_BF16, bool OUT_FP8>
__global__ __launch_bounds__(256) void gemm_mfma_kernel(const float* __restrict__ Af,
                                                        const unsigned short* __restrict__ Ab,
                                                        const unsigned short* __restrict__ Wb,
                                                        const float* __restrict__ bias,
                                                        void* __restrict__ Cout) {
    constexpr int NC = NT * 16;
    int lane = threadIdx.x & 63;
    int wave = (blockIdx.x * 256 + threadIdx.x) >> 6;
    int nwaves = gridDim.x * 4;
    int col = lane & 15;
    int quad = lane >> 4;

    s16x8 bF[NT][4];
#pragma unroll
    for (int t = 0; t < NT; t++)
#pragma unroll
        for (int kb = 0; kb < 4; kb++)
            bF[t][kb] = *(const s16x8*)(Wb + (size_t)((t * 4 + kb) * 64 + lane) * 8);

    const int mtiles = NN / 16;
    for (int mt = wave; mt < mtiles; mt += nwaves) {
        int row = mt * 16 + col;
        s16x8 aF[4];
        if (!A_BF16) {
#pragma unroll
            for (int kb = 0; kb < 4; kb++) {
                const float4* px = (const float4*)(Af + (size_t)row * 128 + kb * 32 + quad * 8);
                float4 f0 = px[0], f1 = px[1];
                unsigned u[4];
                u[0] = bf16pack(f0.x, f0.y);
                u[1] = bf16pack(f0.z, f0.w);
                u[2] = bf16pack(f1.x, f1.y);
                u[3] = bf16pack(f1.z, f1.w);
                aF[kb] = __builtin_bit_cast(s16x8, *(const uint4*)u);
            }
        } else {
#pragma unroll
            for (int kb = 0; kb < 4; kb++) {
                uint4 u = *(const uint4*)(Ab + (size_t)row * 128 + kb * 32 + quad * 8);
                const float4* pb = (const float4*)(bias + kb * 32 + quad * 8);
                float4 b0 = pb[0], b1 = pb[1];
                unsigned r[4];
                r[0] = bf16pack(fmaxf(bf16lo(u.x) + b0.x, 0.f), fmaxf(bf16hi(u.x) + b0.y, 0.f));
                r[1] = bf16pack(fmaxf(bf16lo(u.y) + b0.z, 0.f), fmaxf(bf16hi(u.y) + b0.w, 0.f));
                r[2] = bf16pack(fmaxf(bf16lo(u.z) + b1.x, 0.f), fmaxf(bf16hi(u.z) + b1.y, 0.f));
                r[3] = bf16pack(fmaxf(bf16lo(u.w) + b1.z, 0.f), fmaxf(bf16hi(u.w) + b1.w, 0.f));
                aF[kb] = __builtin_bit_cast(s16x8, *(const uint4*)r);
            }
        }

        f32x4 acc[NT];
#pragma unroll
        for (int t = 0; t < NT; t++) acc[t] = (f32x4){0.f, 0.f, 0.f, 0.f};
#pragma unroll
        for (int kb = 0; kb < 4; kb++)
#pragma unroll
            for (int t = 0; t < NT; t++)
                acc[t] = __builtin_amdgcn_mfma_f32_16x16x32_bf16(aF[kb], bF[t][kb], acc[t], 0, 0, 0);

        int crow = mt * 16 + quad * 4;
        if (OUT_FP8) {
            unsigned char* C8 = (unsigned char*)Cout;
#pragma unroll
            for (int t = 0; t < NT; t++)
#pragma unroll
                for (int r = 0; r < 4; r++)
                    C8[(size_t)(crow + r) * NC + t * 16 + col] = fp8one(acc[t][r]);
        } else {
            unsigned short* C = (unsigned short*)Cout;
#pragma unroll
            for (int t = 0; t < NT; t++)
#pragma unroll
                for (int r = 0; r < 4; r++)
                    C[(size_t)(crow + r) * NC + t * 16 + col] = bf16one(acc[t][r]);
        }
    }
}

// ---------------- SpMM (gather by dst via CSR) ----------------
// Both kernels: row = 128B covered by 16 lanes x 8B. grp = lane>>4 handles
// edge 4j+grp; fixed 16-edge masked iterations -> 4 independent gathers/iter.

// spmm128: X fp8-e4m3 (128 dims), output bf16. Lane g owns dims 8g..8g+7.
__global__ __launch_bounds__(256) void spmm128_kernel(const int* __restrict__ row_ptr,
                                                      const int2* __restrict__ E,
                                                      const uint2* __restrict__ X8,  // 16 granules/row
                                                      uint4* __restrict__ Yb) {      // 16 x 16B/row
    int wid = threadIdx.x >> 6;
    int lane = threadIdx.x & 63;
    int node = blockIdx.x * 4 + wid;
    if (node >= NN) return;
    int e0 = __builtin_amdgcn_readfirstlane(row_ptr[node]);
    int e1 = __builtin_amdgcn_readfirstlane(row_ptr[node + 1]);
    int grp = lane >> 4;
    int g = lane & 15;
    float a[8];
#pragma unroll
    for (int k = 0; k < 8; k++) a[k] = 0.f;

    for (int e = e0; e < e1; e += 16) {
        int2 rec = E[min(e + (lane & 15), e1 - 1)];
        uint2 u[4];
        float v[4];
#pragma unroll
        for (int j = 0; j < 4; j++) {
            int sel = 4 * j + grp;
            int sv = __shfl(rec.x, sel, 64);
            float vv = __builtin_bit_cast(float, __shfl(rec.y, sel, 64));
            if (e + sel >= e1) vv = 0.f;
            v[j] = vv;
            u[j] = X8[(size_t)sv * 16 + g];
        }
#pragma unroll
        for (int j = 0; j < 4; j++) {
            f32x2 p0 = __builtin_amdgcn_cvt_pk_f32_fp8((int)u[j].x, false);
            f32x2 p1 = __builtin_amdgcn_cvt_pk_f32_fp8((int)u[j].x, true);
            f32x2 p2 = __builtin_amdgcn_cvt_pk_f32_fp8((int)u[j].y, false);
            f32x2 p3 = __builtin_amdgcn_cvt_pk_f32_fp8((int)u[j].y, true);
            a[0] += v[j] * p0.x; a[1] += v[j] * p0.y;
            a[2] += v[j] * p1.x; a[3] += v[j] * p1.y;
            a[4] += v[j] * p2.x; a[5] += v[j] * p2.y;
            a[6] += v[j] * p3.x; a[7] += v[j] * p3.y;
        }
    }
#pragma unroll
    for (int k = 0; k < 8; k++) {
        a[k] += __shfl(a[k], lane ^ 16, 64);
        a[k] += __shfl(a[k], lane ^ 32, 64);
    }
    if (grp == 0) {
        uint4 o;
        o.x = bf16pack(a[0], a[1]);
        o.y = bf16pack(a[2], a[3]);
        o.z = bf16pack(a[4], a[5]);
        o.w = bf16pack(a[6], a[7]);
        Yb[(size_t)node * 16 + g] = o;
    }
}

// spmm64: X bf16 (64 dims), fp32 output + bias. Lane g owns dims 4g..4g+3.
__global__ __launch_bounds__(256) void spmm64_kernel(const int* __restrict__ row_ptr,
                                                     const int2* __restrict__ E,
                                                     const uint2* __restrict__ X2,  // 16 granules/row
                                                     const float* __restrict__ b2,
                                                     float* __restrict__ out) {
    int wid = threadIdx.x >> 6;
    int lane = threadIdx.x & 63;
    int node = blockIdx.x * 4 + wid;
    if (node >= NN) return;
    int e0 = __builtin_amdgcn_readfirstlane(row_ptr[node]);
    int e1 = __builtin_amdgcn_readfirstlane(row_ptr[node + 1]);
    int grp = lane >> 4;
    int g = lane & 15;
    float a0 = 0.f, a1 = 0.f, a2 = 0.f, a3 = 0.f;

    for (int e = e0; e < e1; e += 16) {
        int2 rec = E[min(e + (lane & 15), e1 - 1)];
        uint2 u[4];
        float v[4];
#pragma unroll
        for (int j = 0; j < 4; j++) {
            int sel = 4 * j + grp;
            int sv = __shfl(rec.x, sel, 64);
            float vv = __builtin_bit_cast(float, __shfl(rec.y, sel, 64));
            if (e + sel >= e1) vv = 0.f;
            v[j] = vv;
            u[j] = X2[(size_t)sv * 16 + g];
        }
#pragma unroll
        for (int j = 0; j < 4; j++) {
            a0 += v[j] * bf16lo(u[j].x);
            a1 += v[j] * bf16hi(u[j].x);
            a2 += v[j] * bf16lo(u[j].y);
            a3 += v[j] * bf16hi(u[j].y);
        }
    }
    a0 += __shfl(a0, lane ^ 16, 64); a0 += __shfl(a0, lane ^ 32, 64);
    a1 += __shfl(a1, lane ^ 16, 64); a1 += __shfl(a1, lane ^ 32, 64);
    a2 += __shfl(a2, lane ^ 16, 64); a2 += __shfl(a2, lane ^ 32, 64);
    a3 += __shfl(a3, lane ^ 16, 64); a3 += __shfl(a3, lane ^ 32, 64);
    if (grp == 0) {
        const float4 bb = ((const float4*)b2)[g];
        ((float4*)out)[(size_t)node * 16 + g] =
            make_float4(a0 + bb.x, a1 + bb.y, a2 + bb.z, a3 + bb.w);
    }
}

// ---------------- launch ----------------

extern "C" void kernel_launch(void* const* d_in, const int* in_sizes, int n_in,
                              void* d_out, int out_size, void* d_ws, size_t ws_size,
                              hipStream_t stream) {
    const float* x        = (const float*)d_in[0];
    const int*   edge_src = (const int*)d_in[1];
    const int*   edge_dst = (const int*)d_in[2];
    const float* edge_val = (const float*)d_in[3];
    const float* W1       = (const float*)d_in[4];
    const float* b1       = (const float*)d_in[5];
    const float* W2       = (const float*)d_in[6];
    const float* b2       = (const float*)d_in[7];
    float* out = (float*)d_out;

    char* p = (char*)d_ws;
    auto alloc = [&](size_t bytes) {
        char* q = p;
        p += (bytes + 255) & ~(size_t)255;
        return (void*)q;
    };
    unsigned char*  t1  = (unsigned char*)alloc((size_t)NN * 128);       // xW1 fp8; reused as t2
    unsigned short* y1b = (unsigned short*)alloc((size_t)NN * 128 * 2);  // spmm(t1) bf16
    int2* recA          = (int2*)alloc((size_t)NE * 8);   // bucket-partitioned records
    int2* edges         = (int2*)alloc((size_t)NE * 8);   // final CSR records
    int*  ghist         = (int*)alloc((size_t)NB * 4);
    int*  bucketBase    = (int*)alloc((size_t)(NB + 1) * 4);
    int*  gcursor       = (int*)alloc((size_t)NB * 4);
    int*  row_ptr       = (int*)alloc((size_t)(NN + 1) * 4);
    unsigned short* W1b = (unsigned short*)alloc(2048 * 8 * 2);
    unsigned short* W2b = (unsigned short*)alloc(1024 * 8 * 2);
    unsigned short* t2 = (unsigned short*)t1;  // t1 (12.8MB) dead after spmm128; t2 = 12.8MB bf16

    (void)hipMemsetAsync(ghist, 0, (size_t)NB * 4, stream);
    prep_w_kernel<<<12, 256, 0, stream>>>(W1, W2, W1b, W2b);
    coarse_hist<<<(NE + 4095) / 4096, 256, 0, stream>>>(edge_dst, ghist);
    scan_buckets<<<1, 256, 0, stream>>>(ghist, bucketBase, gcursor, row_ptr);
    partition_kernel<<<NCHUNK, 512, 0, stream>>>(edge_src, edge_dst, edge_val, gcursor, recA);
    csr_kernel<<<NB, 512, 0, stream>>>(recA, bucketBase, row_ptr, edges);

    // t1 = fp8(bf16(x) @ W1)
    gemm_mfma_kernel<8, false, true><<<256, 256, 0, stream>>>(x, nullptr, W1b, nullptr, t1);
    // y1b = spmm(t1)  (fp8 gather, bf16 out)
    spmm128_kernel<<<(NN + 3) / 4, 256, 0, stream>>>(row_ptr, edges, (const uint2*)t1, (uint4*)y1b);
    // t2 = relu(y1b + b1) @ W2  (bf16 out)
    gemm_mfma_kernel<4, true, false><<<256, 256, 0, stream>>>(nullptr, y1b, W2b, b1, t2);
    // out = spmm(t2) + b2
    spmm64_kernel<<<(NN + 3) / 4, 256, 0, stream>>>(row_ptr, edges, (const uint2*)t2, b2, out);
}